// Round 3
// baseline (381.945 us; speedup 1.0000x reference)
//
#include <hip/hip_runtime.h>

typedef __bf16 bf16x8 __attribute__((ext_vector_type(8)));
typedef __bf16 bf16x4 __attribute__((ext_vector_type(4)));
typedef __bf16 bf16x2 __attribute__((ext_vector_type(2)));
typedef float  floatx4 __attribute__((ext_vector_type(4)));
typedef unsigned int uint32;
typedef uint32 uintx4 __attribute__((ext_vector_type(4)));

#define MFMA16(a,b,c) __builtin_amdgcn_mfma_f32_16x16x32_bf16(a,b,c,0,0,0)

constexpr int DIM  = 512;
constexpr int SEQ  = 4096;
constexpr int HD   = 64;
// 0.125 (HEAD_DIM^-0.5) * log2(e), folded into Q so softmax uses exp2 directly
constexpr float QSCALE = 0.1803368801111244f;

static __device__ inline __bf16 f2bf(float f) {
    unsigned int u = __builtin_bit_cast(unsigned int, f);
    u += 0x7fffu + ((u >> 16) & 1u);
    return __builtin_bit_cast(__bf16, (unsigned short)(u >> 16));
}
#if __has_builtin(__builtin_amdgcn_cvt_pk_bf16_f32)
static __device__ inline bf16x2 pk2(float a, float b) {
    return __builtin_amdgcn_cvt_pk_bf16_f32(a, b);
}
#else
static __device__ inline bf16x2 pk2(float a, float b) {
    bf16x2 r; r[0] = f2bf(a); r[1] = f2bf(b); return r;
}
#endif
#if __has_builtin(__builtin_amdgcn_exp2f)
#define EXP2(x) __builtin_amdgcn_exp2f(x)
#else
#define EXP2(x) exp2f(x)
#endif
static __device__ inline bf16x8 cvt8(floatx4 lo, floatx4 hi) {
    uintx4 w;
    w[0] = __builtin_bit_cast(uint32, pk2(lo[0], lo[1]));
    w[1] = __builtin_bit_cast(uint32, pk2(lo[2], lo[3]));
    w[2] = __builtin_bit_cast(uint32, pk2(hi[0], hi[1]));
    w[3] = __builtin_bit_cast(uint32, pk2(hi[2], hi[3]));
    return __builtin_bit_cast(bf16x8, w);
}

// async global->LDS, 16B per lane; LDS dest = wave-uniform base + lane*16B
static __device__ inline void gload16(const __bf16* g, __bf16* l) {
#if __has_builtin(__builtin_amdgcn_global_load_lds)
    __builtin_amdgcn_global_load_lds(
        (const __attribute__((address_space(1))) unsigned int*)g,
        (__attribute__((address_space(3))) unsigned int*)l, 16, 0, 0);
#else
    *(bf16x8*)(l + (threadIdx.x & 63)*8) = *(const bf16x8*)g;
#endif
}

// Blocked fragment layout for Q and K (A/B-operand ready, b128 loads):
//   blk[bh][s>>4][d>>5][lane][8], lane = ((d>>3)&3)*16 + (s&15), slot = d&7
// V blocked under key-permutation pi(q,j)=16*(j>=4)+4q+(j&3):
//   Vblk[bh][s>>5][d>>4][lane][8], lane = ((s>>2)&3)*16 + (d&15),
//   slot j = (s&3) + ((s>>4)&1)*4.

// ---------------------------------------------------------------------------
// Stage 1: qkv = x @ w_qkv^T + b_qkv.  (unchanged from R1: double-buffered
// LDS, 1 barrier/iter, reg prefetch of next fp32 panel)
// ---------------------------------------------------------------------------
__global__ __launch_bounds__(256)
void gemm_qkv(const float* __restrict__ X, const float* __restrict__ W,
              const float* __restrict__ bias,
              __bf16* __restrict__ Qb, __bf16* __restrict__ Kb, __bf16* __restrict__ Vb)
{
    __shared__ __bf16 As[2][128*32];
    __shared__ __bf16 Bs[2][128*32];
    const int tid  = threadIdx.x;
    const int lane = tid & 63;
    const int wave = tid >> 6;
    const int quad = lane >> 4;
    const int l16  = lane & 15;
    const int waveM = wave >> 1, waveN = wave & 1;
    const int mBase = blockIdx.x * 128;
    const int nBase = blockIdx.y * 128;
    const int which = nBase >> 9;          // 0=q 1=k 2=v (uniform per block)

    floatx4 zero = {0.f, 0.f, 0.f, 0.f};
    floatx4 acc[4][4];
    for (int i = 0; i < 4; i++)
        for (int j = 0; j < 4; j++) acc[i][j] = zero;

    const int srow = tid >> 2;        // 0..63
    const int scol = (tid & 3) * 8;   // 0,8,16,24

    const float* xp0 = X + (size_t)(mBase + srow)      * DIM + scol;
    const float* xp1 = X + (size_t)(mBase + 64 + srow) * DIM + scol;
    const float* wp0 = W + (size_t)(nBase + srow)      * DIM + scol;
    const float* wp1 = W + (size_t)(nBase + 64 + srow) * DIM + scol;

    floatx4 r[8];
    auto LOAD = [&](int k0) {
        r[0] = *(const floatx4*)(xp0 + k0); r[1] = *(const floatx4*)(xp0 + k0 + 4);
        r[2] = *(const floatx4*)(xp1 + k0); r[3] = *(const floatx4*)(xp1 + k0 + 4);
        r[4] = *(const floatx4*)(wp0 + k0); r[5] = *(const floatx4*)(wp0 + k0 + 4);
        r[6] = *(const floatx4*)(wp1 + k0); r[7] = *(const floatx4*)(wp1 + k0 + 4);
    };
    auto STORE = [&](int b) {
        *(bf16x8*)&As[b][srow*32 + scol]      = cvt8(r[0], r[1]);
        *(bf16x8*)&As[b][(64+srow)*32 + scol] = cvt8(r[2], r[3]);
        *(bf16x8*)&Bs[b][srow*32 + scol]      = cvt8(r[4], r[5]);
        *(bf16x8*)&Bs[b][(64+srow)*32 + scol] = cvt8(r[6], r[7]);
    };

    LOAD(0);
    STORE(0);
    __syncthreads();

    for (int it = 0; it < 16; ++it) {
        const int cur = it & 1;
        if (it < 15) LOAD((it + 1) * 32);   // prefetch next panel (hidden latency)

        bf16x8 af[4], bfr[4];
        for (int mi = 0; mi < 4; mi++)
            af[mi]  = *(const bf16x8*)&As[cur][(waveM*64 + mi*16 + l16)*32 + quad*8];
        for (int ni = 0; ni < 4; ni++)
            bfr[ni] = *(const bf16x8*)&Bs[cur][(waveN*64 + ni*16 + l16)*32 + quad*8];
        if (which == 2) {
            for (int mi = 0; mi < 4; mi++)
                for (int ni = 0; ni < 4; ni++)
                    acc[mi][ni] = MFMA16(af[mi], bfr[ni], acc[mi][ni]);
        } else {
            // transposed: rows = W-rows (d), cols = X-rows (s)
            for (int mi = 0; mi < 4; mi++)
                for (int ni = 0; ni < 4; ni++)
                    acc[mi][ni] = MFMA16(bfr[ni], af[mi], acc[mi][ni]);
        }
        if (it < 15) STORE(cur ^ 1);        // writes go to the other buffer
        __syncthreads();                    // one barrier per iter
    }

    if (which == 2) {
        // V epilogue (normal orientation): rows = s, cols = n/d
        for (int ni = 0; ni < 4; ni++) {
            const int n = nBase + waveN*64 + ni*16 + l16;
            const float bv = bias[n];
            const int h = (n >> 6) & 7;
            const int d = n & 63;
            for (int mi = 0; mi < 4; mi++) {
                const int m0 = mBase + waveM*64 + mi*16 + quad*4;
                const int b  = m0 >> 12;
                const int s0 = m0 & 4095;
                const int bh = (b << 3) | h;
                bf16x4 v;
                for (int rr = 0; rr < 4; rr++) v[rr] = f2bf(acc[mi][ni][rr] + bv);
                size_t off = (((((size_t)bh*128 + (s0 >> 5))*4 + (d >> 4))*64)
                              + ((s0 >> 2) & 3)*16 + (d & 15))*8 + ((s0 >> 4) & 1)*4;
                *(bf16x4*)&Vb[off] = v;
            }
        }
    } else {
        // Q/K epilogue (transposed): rows = d (quad*4+r), cols = s (l16)
        __bf16* dst = (which == 0) ? Qb : Kb;
        for (int ni = 0; ni < 4; ni++) {
            const int n0 = nBase + waveN*64 + ni*16 + quad*4;
            const floatx4 b4 = *(const floatx4*)&bias[n0];
            const int dfull = n0 & 511;           // 0..511 within q or k section
            const int h  = dfull >> 6;
            const int d0 = dfull & 63;            // 4-aligned
            const int lgrp = ((d0 >> 3) & 3)*16 + l16;
            const int half = d0 >> 5;
            const int slot = d0 & 7;              // 0 or 4
            for (int mi = 0; mi < 4; mi++) {
                const int m = mBase + waveM*64 + mi*16 + l16;
                const int b = m >> 12, s = m & 4095;
                const int bh = (b << 3) | h;
                bf16x4 v;
                for (int rr = 0; rr < 4; rr++) {
                    float val = acc[mi][ni][rr] + b4[rr];
                    if (which == 0) val *= QSCALE;
                    v[rr] = f2bf(val);
                }
                size_t off = ((((size_t)bh*256 + (s >> 4))*2 + half)*64 + lgrp)*8 + slot;
                *(bf16x4*)&dst[off] = v;
            }
        }
    }
}

// ---------------------------------------------------------------------------
// Stage 2: flash attention — R0 verified core (best measured: 82 µs), with
// ONE change: __launch_bounds__(256,4).  Grid is 16x64 = 1024 blocks = exactly
// 4 blocks/CU; at 3 blocks/CU this ran as 768 + ragged 256 (24% avg
// occupancy).  4/CU -> one clean full round, 4 waves/SIMD of latency hiding.
// VGPR was 84 (cap for 4 waves/EU is 128 -> no spill), LDS 27136*4 < 160K.
// ---------------------------------------------------------------------------
__global__ __launch_bounds__(256, 4)
void attn_kernel(const __bf16* __restrict__ Qb, const __bf16* __restrict__ Kb,
                 const __bf16* __restrict__ Vb, __bf16* __restrict__ Ao)
{
    __shared__ __bf16 Ob[3][64*68];   // bf16 partial O^T, stride 68
    __shared__ float  Lb[4][64];
    const int tid  = threadIdx.x;
    const int lane = tid & 63;
    const int wave = tid >> 6;
    const int quad = lane >> 4;
    const int l16  = lane & 15;
    const int bh    = blockIdx.x;         // 0..15
    const int qBase = blockIdx.y * 64;

    const __bf16* qg = Qb + (size_t)bh*256*2*512;
    const __bf16* kg = Kb + (size_t)bh*256*2*512;
    const __bf16* vg = Vb + (size_t)bh*128*4*512;

    bf16x8 qf[4][2];
    for (int t = 0; t < 4; t++)
        for (int hb = 0; hb < 2; hb++)
            qf[t][hb] = *(const bf16x8*)(qg
                + ((size_t)((qBase >> 4) + t)*2 + hb)*512 + lane*8);

    floatx4 zero = {0.f, 0.f, 0.f, 0.f};
    floatx4 oacc[4][4];   // [t][od]: O^T tile, row d=od*16+quad*4+r, col q=t*16+l16
    for (int t = 0; t < 4; t++)
        for (int od = 0; od < 4; od++) oacc[t][od] = zero;
    floatx4 Lt[4];        // ones-MFMA: every row of Lt[t] = L[q=t*16+l16]
    for (int t = 0; t < 4; t++) Lt[t] = zero;

    bf16x8 ones;
    for (int j = 0; j < 8; j++) ones[j] = f2bf(1.0f);

    const int key_begin = wave * 1024;
    const __bf16* kptr = kg + (size_t)(key_begin >> 4)*1024 + lane*8;
    const __bf16* vptr = vg + (size_t)(key_begin >> 5)*2048 + lane*8;

    for (int c = 0; c < 32; ++c) {
        bf16x8 kb00 = *(const bf16x8*)(kptr);
        bf16x8 kb01 = *(const bf16x8*)(kptr + 512);
        bf16x8 kb10 = *(const bf16x8*)(kptr + 1024);
        bf16x8 kb11 = *(const bf16x8*)(kptr + 1536);
        bf16x8 vb0  = *(const bf16x8*)(vptr);
        bf16x8 vb1  = *(const bf16x8*)(vptr + 512);
        bf16x8 vb2  = *(const bf16x8*)(vptr + 1024);
        bf16x8 vb3  = *(const bf16x8*)(vptr + 1536);
        kptr += 2048;
        vptr += 2048;

        for (int t = 0; t < 4; t++) {
            floatx4 z0 = zero, z1 = zero;
            z0 = MFMA16(kb00, qf[t][0], z0);
            z0 = MFMA16(kb01, qf[t][1], z0);
            z1 = MFMA16(kb10, qf[t][0], z1);
            z1 = MFMA16(kb11, qf[t][1], z1);
            float e0[4], e1[4];
            for (int r = 0; r < 4; r++) { e0[r] = EXP2(z0[r]); e1[r] = EXP2(z1[r]); }
            uintx4 w;
            w[0] = __builtin_bit_cast(uint32, pk2(e0[0], e0[1]));
            w[1] = __builtin_bit_cast(uint32, pk2(e0[2], e0[3]));
            w[2] = __builtin_bit_cast(uint32, pk2(e1[0], e1[1]));
            w[3] = __builtin_bit_cast(uint32, pk2(e1[2], e1[3]));
            bf16x8 pb = __builtin_bit_cast(bf16x8, w);
            Lt[t] = MFMA16(ones, pb, Lt[t]);
            oacc[t][0] = MFMA16(vb0, pb, oacc[t][0]);
            oacc[t][1] = MFMA16(vb1, pb, oacc[t][1]);
            oacc[t][2] = MFMA16(vb2, pb, oacc[t][2]);
            oacc[t][3] = MFMA16(vb3, pb, oacc[t][3]);
        }
    }

    // L[q] is replicated across rows of Lt[t]; publish per-wave partials
    if (lane < 16)
        for (int t = 0; t < 4; t++) Lb[wave][t*16 + lane] = Lt[t][0];
    __syncthreads();
    float inv[4];
    for (int t = 0; t < 4; t++) {
        const int q = t*16 + l16;
        inv[t] = 1.0f / (Lb[0][q] + Lb[1][q] + Lb[2][q] + Lb[3][q]);
    }
    if (wave != 0) {
        for (int t = 0; t < 4; t++)
            for (int od = 0; od < 4; od++) {
                bf16x4 v;
                for (int r = 0; r < 4; r++) v[r] = f2bf(oacc[t][od][r] * inv[t]);
                *(bf16x4*)&Ob[wave-1][(t*16 + l16)*68 + od*16 + quad*4] = v;
            }
    }
    __syncthreads();
    if (wave == 0) {
        const int b = bh >> 3, h = bh & 7;
        for (int t = 0; t < 4; t++) {
            const int s = qBase + t*16 + l16;
            for (int od = 0; od < 4; od++) {
                bf16x4 o0 = *(const bf16x4*)&Ob[0][(t*16 + l16)*68 + od*16 + quad*4];
                bf16x4 o1 = *(const bf16x4*)&Ob[1][(t*16 + l16)*68 + od*16 + quad*4];
                bf16x4 o2 = *(const bf16x4*)&Ob[2][(t*16 + l16)*68 + od*16 + quad*4];
                bf16x4 v;
                for (int r = 0; r < 4; r++) {
                    float o = oacc[t][od][r] * inv[t] +
                              (float)o0[r] + (float)o1[r] + (float)o2[r];
                    v[r] = f2bf(o);
                }
                *(bf16x4*)&Ao[((size_t)(b*SEQ + s))*DIM + h*HD + od*16 + quad*4] = v;
            }
        }
    }
}

// ---------------------------------------------------------------------------
// Stage 3: out = attn_out @ w_proj^T + b_proj.  (unchanged from R1: 64x64
// tiles, grid (128,8), double-buffered LDS, A via global_load_lds, W reg-
// prefetched + inline cvt, one barrier per k-iter)
// ---------------------------------------------------------------------------
__global__ __launch_bounds__(256)
void gemm_proj(const __bf16* __restrict__ A, const float* __restrict__ W,
               const float* __restrict__ bias, float* __restrict__ Out)
{
    __shared__ __bf16 As[2][64*32];
    __shared__ __bf16 Bs[2][64*32];
    const int tid  = threadIdx.x;
    const int lane = tid & 63;
    const int wave = tid >> 6;
    const int quad = lane >> 4;
    const int l16  = lane & 15;
    const int waveM = wave >> 1, waveN = wave & 1;
    const int mBase = blockIdx.x * 64;
    const int nBase = blockIdx.y * 64;

    floatx4 zero = {0.f, 0.f, 0.f, 0.f};
    floatx4 acc[2][2];
    for (int i = 0; i < 2; i++)
        for (int j = 0; j < 2; j++) acc[i][j] = zero;

    const int srow = tid >> 2;          // 0..63
    const int scol = (tid & 3) * 8;     // 0,8,16,24

    const __bf16* gA = A + (size_t)(mBase + wave*16 + (lane >> 2))*DIM + (lane & 3)*8;
    const float*  gW = W + (size_t)(nBase + srow)*DIM + scol;

    floatx4 rw0, rw1;
    gload16(gA, &As[0][wave*512]);
    rw0 = *(const floatx4*)(gW);
    rw1 = *(const floatx4*)(gW + 4);
    *(bf16x8*)&Bs[0][srow*32 + scol] = cvt8(rw0, rw1);
    __syncthreads();

    for (int it = 0; it < 16; ++it) {
        const int cur = it & 1;
        if (it < 15) {
            gload16(gA + (it + 1)*32, &As[cur ^ 1][wave*512]);
            rw0 = *(const floatx4*)(gW + (it + 1)*32);
            rw1 = *(const floatx4*)(gW + (it + 1)*32 + 4);
        }
        bf16x8 af[2], bfr[2];
        for (int mi = 0; mi < 2; mi++)
            af[mi]  = *(const bf16x8*)&As[cur][(waveM*32 + mi*16 + l16)*32 + quad*8];
        for (int ni = 0; ni < 2; ni++)
            bfr[ni] = *(const bf16x8*)&Bs[cur][(waveN*32 + ni*16 + l16)*32 + quad*8];
        for (int mi = 0; mi < 2; mi++)
            for (int ni = 0; ni < 2; ni++)
                acc[mi][ni] = MFMA16(af[mi], bfr[ni], acc[mi][ni]);
        if (it < 15)
            *(bf16x8*)&Bs[cur ^ 1][srow*32 + scol] = cvt8(rw0, rw1);
        __syncthreads();   // drains gload_lds (vmcnt) and ds_writes
    }

    for (int ni = 0; ni < 2; ni++) {
        const int n = nBase + waveN*32 + ni*16 + l16;
        const float bv = bias[n];
        for (int mi = 0; mi < 2; mi++) {
            const int m0 = mBase + waveM*32 + mi*16 + quad*4;
            for (int rr = 0; rr < 4; rr++)
                Out[(size_t)(m0 + rr)*DIM + n] = acc[mi][ni][rr] + bv;
        }
    }
}

extern "C" void kernel_launch(void* const* d_in, const int* in_sizes, int n_in,
                              void* d_out, int out_size, void* d_ws, size_t ws_size,
                              hipStream_t stream) {
    const float* x      = (const float*)d_in[0];   // [2,4096,512] fp32
    const float* w_qkv  = (const float*)d_in[1];   // [1536,512] fp32
    const float* b_qkv  = (const float*)d_in[2];   // [1536] fp32
    const float* w_proj = (const float*)d_in[3];   // [512,512] fp32
    const float* b_proj = (const float*)d_in[4];   // [512] fp32
    float* out = (float*)d_out;                    // [2,4096,512] fp32

    __bf16* ws  = (__bf16*)d_ws;
    const size_t PLANE = (size_t)16 * SEQ * HD;    // 4 Mi elements = 8 MB
    __bf16* Qbk = ws;                 // Qblk [16][256][2][64][8] (pre-scaled)
    __bf16* Kbk = ws + PLANE;         // Kblk [16][256][2][64][8]
    __bf16* Vbk = ws + 2*PLANE;       // Vblk [16][128][4][64][8]
    __bf16* Aob = ws + 3*PLANE;       // [2,4096,512] attention output (bf16)

    gemm_qkv<<<dim3(64, 12), 256, 0, stream>>>(x, w_qkv, b_qkv, Qbk, Kbk, Vbk);
    attn_kernel<<<dim3(16, 64), 256, 0, stream>>>(Qbk, Kbk, Vbk, Aob);
    gemm_proj<<<dim3(128, 8), 256, 0, stream>>>(Aob, w_proj, b_proj, out);
}

// Round 5
// 210.972 us; speedup vs baseline: 1.8104x; 1.8104x over previous
//
#include <hip/hip_runtime.h>

typedef __bf16 bf16x8 __attribute__((ext_vector_type(8)));
typedef __bf16 bf16x4 __attribute__((ext_vector_type(4)));
typedef __bf16 bf16x2 __attribute__((ext_vector_type(2)));
typedef float  floatx4 __attribute__((ext_vector_type(4)));
typedef unsigned int uint32;
typedef uint32 uintx4 __attribute__((ext_vector_type(4)));

#define MFMA16(a,b,c) __builtin_amdgcn_mfma_f32_16x16x32_bf16(a,b,c,0,0,0)

constexpr int DIM  = 512;
constexpr int SEQ  = 4096;
constexpr int HD   = 64;
// 0.125 (HEAD_DIM^-0.5) * log2(e), folded into Q so softmax uses exp2 directly
constexpr float QSCALE = 0.1803368801111244f;

static __device__ inline __bf16 f2bf(float f) {
    unsigned int u = __builtin_bit_cast(unsigned int, f);
    u += 0x7fffu + ((u >> 16) & 1u);
    return __builtin_bit_cast(__bf16, (unsigned short)(u >> 16));
}
#if __has_builtin(__builtin_amdgcn_cvt_pk_bf16_f32)
static __device__ inline bf16x2 pk2(float a, float b) {
    return __builtin_amdgcn_cvt_pk_bf16_f32(a, b);
}
#else
static __device__ inline bf16x2 pk2(float a, float b) {
    bf16x2 r; r[0] = f2bf(a); r[1] = f2bf(b); return r;
}
#endif
#if __has_builtin(__builtin_amdgcn_exp2f)
#define EXP2(x) __builtin_amdgcn_exp2f(x)
#else
#define EXP2(x) exp2f(x)
#endif
static __device__ inline bf16x8 cvt8(floatx4 lo, floatx4 hi) {
    uintx4 w;
    w[0] = __builtin_bit_cast(uint32, pk2(lo[0], lo[1]));
    w[1] = __builtin_bit_cast(uint32, pk2(lo[2], lo[3]));
    w[2] = __builtin_bit_cast(uint32, pk2(hi[0], hi[1]));
    w[3] = __builtin_bit_cast(uint32, pk2(hi[2], hi[3]));
    return __builtin_bit_cast(bf16x8, w);
}

// async global->LDS, 16B per lane; LDS dest = wave-uniform base + lane*16B
static __device__ inline void gload16(const __bf16* g, __bf16* l) {
#if __has_builtin(__builtin_amdgcn_global_load_lds)
    __builtin_amdgcn_global_load_lds(
        (const __attribute__((address_space(1))) unsigned int*)g,
        (__attribute__((address_space(3))) unsigned int*)l, 16, 0, 0);
#else
    *(bf16x8*)(l + (threadIdx.x & 63)*8) = *(const bf16x8*)g;
#endif
}

// Blocked fragment layout for Q and K (A/B-operand ready, b128 loads):
//   blk[bh][s>>4][d>>5][lane][8], lane = ((d>>3)&3)*16 + (s&15), slot = d&7
// V blocked under key-permutation pi(q,j)=16*(j>=4)+4q+(j&3):
//   Vblk[bh][s>>5][d>>4][lane][8], lane = ((s>>2)&3)*16 + (d&15),
//   slot j = (s&3) + ((s>>4)&1)*4.

// ---------------------------------------------------------------------------
// Stage 1: qkv = x @ w_qkv^T + b_qkv.  (unchanged from R1: double-buffered
// LDS, 1 barrier/iter, reg prefetch of next fp32 panel)
// ---------------------------------------------------------------------------
__global__ __launch_bounds__(256)
void gemm_qkv(const float* __restrict__ X, const float* __restrict__ W,
              const float* __restrict__ bias,
              __bf16* __restrict__ Qb, __bf16* __restrict__ Kb, __bf16* __restrict__ Vb)
{
    __shared__ __bf16 As[2][128*32];
    __shared__ __bf16 Bs[2][128*32];
    const int tid  = threadIdx.x;
    const int lane = tid & 63;
    const int wave = tid >> 6;
    const int quad = lane >> 4;
    const int l16  = lane & 15;
    const int waveM = wave >> 1, waveN = wave & 1;
    const int mBase = blockIdx.x * 128;
    const int nBase = blockIdx.y * 128;
    const int which = nBase >> 9;          // 0=q 1=k 2=v (uniform per block)

    floatx4 zero = {0.f, 0.f, 0.f, 0.f};
    floatx4 acc[4][4];
    for (int i = 0; i < 4; i++)
        for (int j = 0; j < 4; j++) acc[i][j] = zero;

    const int srow = tid >> 2;        // 0..63
    const int scol = (tid & 3) * 8;   // 0,8,16,24

    const float* xp0 = X + (size_t)(mBase + srow)      * DIM + scol;
    const float* xp1 = X + (size_t)(mBase + 64 + srow) * DIM + scol;
    const float* wp0 = W + (size_t)(nBase + srow)      * DIM + scol;
    const float* wp1 = W + (size_t)(nBase + 64 + srow) * DIM + scol;

    floatx4 r[8];
    auto LOAD = [&](int k0) {
        r[0] = *(const floatx4*)(xp0 + k0); r[1] = *(const floatx4*)(xp0 + k0 + 4);
        r[2] = *(const floatx4*)(xp1 + k0); r[3] = *(const floatx4*)(xp1 + k0 + 4);
        r[4] = *(const floatx4*)(wp0 + k0); r[5] = *(const floatx4*)(wp0 + k0 + 4);
        r[6] = *(const floatx4*)(wp1 + k0); r[7] = *(const floatx4*)(wp1 + k0 + 4);
    };
    auto STORE = [&](int b) {
        *(bf16x8*)&As[b][srow*32 + scol]      = cvt8(r[0], r[1]);
        *(bf16x8*)&As[b][(64+srow)*32 + scol] = cvt8(r[2], r[3]);
        *(bf16x8*)&Bs[b][srow*32 + scol]      = cvt8(r[4], r[5]);
        *(bf16x8*)&Bs[b][(64+srow)*32 + scol] = cvt8(r[6], r[7]);
    };

    LOAD(0);
    STORE(0);
    __syncthreads();

    for (int it = 0; it < 16; ++it) {
        const int cur = it & 1;
        if (it < 15) LOAD((it + 1) * 32);   // prefetch next panel (hidden latency)

        bf16x8 af[4], bfr[4];
        for (int mi = 0; mi < 4; mi++)
            af[mi]  = *(const bf16x8*)&As[cur][(waveM*64 + mi*16 + l16)*32 + quad*8];
        for (int ni = 0; ni < 4; ni++)
            bfr[ni] = *(const bf16x8*)&Bs[cur][(waveN*64 + ni*16 + l16)*32 + quad*8];
        if (which == 2) {
            for (int mi = 0; mi < 4; mi++)
                for (int ni = 0; ni < 4; ni++)
                    acc[mi][ni] = MFMA16(af[mi], bfr[ni], acc[mi][ni]);
        } else {
            // transposed: rows = W-rows (d), cols = X-rows (s)
            for (int mi = 0; mi < 4; mi++)
                for (int ni = 0; ni < 4; ni++)
                    acc[mi][ni] = MFMA16(bfr[ni], af[mi], acc[mi][ni]);
        }
        if (it < 15) STORE(cur ^ 1);        // writes go to the other buffer
        __syncthreads();                    // one barrier per iter
    }

    if (which == 2) {
        // V epilogue (normal orientation): rows = s, cols = n/d
        for (int ni = 0; ni < 4; ni++) {
            const int n = nBase + waveN*64 + ni*16 + l16;
            const float bv = bias[n];
            const int h = (n >> 6) & 7;
            const int d = n & 63;
            for (int mi = 0; mi < 4; mi++) {
                const int m0 = mBase + waveM*64 + mi*16 + quad*4;
                const int b  = m0 >> 12;
                const int s0 = m0 & 4095;
                const int bh = (b << 3) | h;
                bf16x4 v;
                for (int rr = 0; rr < 4; rr++) v[rr] = f2bf(acc[mi][ni][rr] + bv);
                size_t off = (((((size_t)bh*128 + (s0 >> 5))*4 + (d >> 4))*64)
                              + ((s0 >> 2) & 3)*16 + (d & 15))*8 + ((s0 >> 4) & 1)*4;
                *(bf16x4*)&Vb[off] = v;
            }
        }
    } else {
        // Q/K epilogue (transposed): rows = d (quad*4+r), cols = s (l16)
        __bf16* dst = (which == 0) ? Qb : Kb;
        for (int ni = 0; ni < 4; ni++) {
            const int n0 = nBase + waveN*64 + ni*16 + quad*4;
            const floatx4 b4 = *(const floatx4*)&bias[n0];
            const int dfull = n0 & 511;           // 0..511 within q or k section
            const int h  = dfull >> 6;
            const int d0 = dfull & 63;            // 4-aligned
            const int lgrp = ((d0 >> 3) & 3)*16 + l16;
            const int half = d0 >> 5;
            const int slot = d0 & 7;              // 0 or 4
            for (int mi = 0; mi < 4; mi++) {
                const int m = mBase + waveM*64 + mi*16 + l16;
                const int b = m >> 12, s = m & 4095;
                const int bh = (b << 3) | h;
                bf16x4 v;
                for (int rr = 0; rr < 4; rr++) {
                    float val = acc[mi][ni][rr] + b4[rr];
                    if (which == 0) val *= QSCALE;
                    v[rr] = f2bf(val);
                }
                size_t off = ((((size_t)bh*256 + (s >> 4))*2 + half)*64 + lgrp)*8 + slot;
                *(bf16x4*)&dst[off] = v;
            }
        }
    }
}

// ---------------------------------------------------------------------------
// Stage 2: flash attention — R0 verified core (82 µs best), launch_bounds
// (256,3) [NOT 4: unified VGPR+AGPR file -> ~164 regs/wave; 4 waves/EU caps
// at 128 and spills to scratch: R3 measured FETCH 530MB, 267 µs].
// R4/R5 change: 1D grid + head->XCD clustering swizzle.  Old dim3(16,64) had
// bh fastest-varying -> every XCD hosted all 16 heads = 16MB K/V working set
// thrashing 4MB L2 -> K/V served by L3 (~12.5 TB/s observed).  New mapping
// puts all 64 q-blocks of a head on one XCD (2 heads = 2MB < 4MB L2).
// (R4 bench was an infra failure — container died; identical resubmit.)
// ---------------------------------------------------------------------------
__global__ __launch_bounds__(256, 3)
void attn_kernel(const __bf16* __restrict__ Qb, const __bf16* __restrict__ Kb,
                 const __bf16* __restrict__ Vb, __bf16* __restrict__ Ao)
{
    __shared__ __bf16 Ob[3][64*68];   // bf16 partial O^T, stride 68
    __shared__ float  Lb[4][64];
    const int tid  = threadIdx.x;
    const int lane = tid & 63;
    const int wave = tid >> 6;
    const int quad = lane >> 4;
    const int l16  = lane & 15;
    // XCD-clustering swizzle: id%8 selects XCD (round-robin dispatch); keep
    // it constant per head.  bh = (id&7) + 8*(slot>=64), qb = slot&63.
    const int id    = blockIdx.x;          // 0..1023
    const int slot  = id >> 3;             // 0..127
    const int bh    = (id & 7) + ((slot >> 6) << 3);
    const int qBase = (slot & 63) * 64;

    const __bf16* qg = Qb + (size_t)bh*256*2*512;
    const __bf16* kg = Kb + (size_t)bh*256*2*512;
    const __bf16* vg = Vb + (size_t)bh*128*4*512;

    bf16x8 qf[4][2];
    for (int t = 0; t < 4; t++)
        for (int hb = 0; hb < 2; hb++)
            qf[t][hb] = *(const bf16x8*)(qg
                + ((size_t)((qBase >> 4) + t)*2 + hb)*512 + lane*8);

    floatx4 zero = {0.f, 0.f, 0.f, 0.f};
    floatx4 oacc[4][4];   // [t][od]: O^T tile, row d=od*16+quad*4+r, col q=t*16+l16
    for (int t = 0; t < 4; t++)
        for (int od = 0; od < 4; od++) oacc[t][od] = zero;
    floatx4 Lt[4];        // ones-MFMA: every row of Lt[t] = L[q=t*16+l16]
    for (int t = 0; t < 4; t++) Lt[t] = zero;

    bf16x8 ones;
    for (int j = 0; j < 8; j++) ones[j] = f2bf(1.0f);

    const int key_begin = wave * 1024;
    const __bf16* kptr = kg + (size_t)(key_begin >> 4)*1024 + lane*8;
    const __bf16* vptr = vg + (size_t)(key_begin >> 5)*2048 + lane*8;

    for (int c = 0; c < 32; ++c) {
        bf16x8 kb00 = *(const bf16x8*)(kptr);
        bf16x8 kb01 = *(const bf16x8*)(kptr + 512);
        bf16x8 kb10 = *(const bf16x8*)(kptr + 1024);
        bf16x8 kb11 = *(const bf16x8*)(kptr + 1536);
        bf16x8 vb0  = *(const bf16x8*)(vptr);
        bf16x8 vb1  = *(const bf16x8*)(vptr + 512);
        bf16x8 vb2  = *(const bf16x8*)(vptr + 1024);
        bf16x8 vb3  = *(const bf16x8*)(vptr + 1536);
        kptr += 2048;
        vptr += 2048;

        for (int t = 0; t < 4; t++) {
            floatx4 z0 = zero, z1 = zero;
            z0 = MFMA16(kb00, qf[t][0], z0);
            z0 = MFMA16(kb01, qf[t][1], z0);
            z1 = MFMA16(kb10, qf[t][0], z1);
            z1 = MFMA16(kb11, qf[t][1], z1);
            float e0[4], e1[4];
            for (int r = 0; r < 4; r++) { e0[r] = EXP2(z0[r]); e1[r] = EXP2(z1[r]); }
            uintx4 w;
            w[0] = __builtin_bit_cast(uint32, pk2(e0[0], e0[1]));
            w[1] = __builtin_bit_cast(uint32, pk2(e0[2], e0[3]));
            w[2] = __builtin_bit_cast(uint32, pk2(e1[0], e1[1]));
            w[3] = __builtin_bit_cast(uint32, pk2(e1[2], e1[3]));
            bf16x8 pb = __builtin_bit_cast(bf16x8, w);
            Lt[t] = MFMA16(ones, pb, Lt[t]);
            oacc[t][0] = MFMA16(vb0, pb, oacc[t][0]);
            oacc[t][1] = MFMA16(vb1, pb, oacc[t][1]);
            oacc[t][2] = MFMA16(vb2, pb, oacc[t][2]);
            oacc[t][3] = MFMA16(vb3, pb, oacc[t][3]);
        }
    }

    // L[q] is replicated across rows of Lt[t]; publish per-wave partials
    if (lane < 16)
        for (int t = 0; t < 4; t++) Lb[wave][t*16 + lane] = Lt[t][0];
    __syncthreads();
    float inv[4];
    for (int t = 0; t < 4; t++) {
        const int q = t*16 + l16;
        inv[t] = 1.0f / (Lb[0][q] + Lb[1][q] + Lb[2][q] + Lb[3][q]);
    }
    if (wave != 0) {
        for (int t = 0; t < 4; t++)
            for (int od = 0; od < 4; od++) {
                bf16x4 v;
                for (int r = 0; r < 4; r++) v[r] = f2bf(oacc[t][od][r] * inv[t]);
                *(bf16x4*)&Ob[wave-1][(t*16 + l16)*68 + od*16 + quad*4] = v;
            }
    }
    __syncthreads();
    if (wave == 0) {
        const int b = bh >> 3, h = bh & 7;
        for (int t = 0; t < 4; t++) {
            const int s = qBase + t*16 + l16;
            for (int od = 0; od < 4; od++) {
                bf16x4 o0 = *(const bf16x4*)&Ob[0][(t*16 + l16)*68 + od*16 + quad*4];
                bf16x4 o1 = *(const bf16x4*)&Ob[1][(t*16 + l16)*68 + od*16 + quad*4];
                bf16x4 o2 = *(const bf16x4*)&Ob[2][(t*16 + l16)*68 + od*16 + quad*4];
                bf16x4 v;
                for (int r = 0; r < 4; r++) {
                    float o = oacc[t][od][r] * inv[t] +
                              (float)o0[r] + (float)o1[r] + (float)o2[r];
                    v[r] = f2bf(o);
                }
                *(bf16x4*)&Ao[((size_t)(b*SEQ + s))*DIM + h*HD + od*16 + quad*4] = v;
            }
        }
    }
}

// ---------------------------------------------------------------------------
// Stage 3: out = attn_out @ w_proj^T + b_proj.  (unchanged from R1: 64x64
// tiles, grid (128,8), double-buffered LDS, A via global_load_lds, W reg-
// prefetched + inline cvt, one barrier per k-iter)
// ---------------------------------------------------------------------------
__global__ __launch_bounds__(256)
void gemm_proj(const __bf16* __restrict__ A, const float* __restrict__ W,
               const float* __restrict__ bias, float* __restrict__ Out)
{
    __shared__ __bf16 As[2][64*32];
    __shared__ __bf16 Bs[2][64*32];
    const int tid  = threadIdx.x;
    const int lane = tid & 63;
    const int wave = tid >> 6;
    const int quad = lane >> 4;
    const int l16  = lane & 15;
    const int waveM = wave >> 1, waveN = wave & 1;
    const int mBase = blockIdx.x * 64;
    const int nBase = blockIdx.y * 64;

    floatx4 zero = {0.f, 0.f, 0.f, 0.f};
    floatx4 acc[2][2];
    for (int i = 0; i < 2; i++)
        for (int j = 0; j < 2; j++) acc[i][j] = zero;

    const int srow = tid >> 2;          // 0..63
    const int scol = (tid & 3) * 8;     // 0,8,16,24

    const __bf16* gA = A + (size_t)(mBase + wave*16 + (lane >> 2))*DIM + (lane & 3)*8;
    const float*  gW = W + (size_t)(nBase + srow)*DIM + scol;

    floatx4 rw0, rw1;
    gload16(gA, &As[0][wave*512]);
    rw0 = *(const floatx4*)(gW);
    rw1 = *(const floatx4*)(gW + 4);
    *(bf16x8*)&Bs[0][srow*32 + scol] = cvt8(rw0, rw1);
    __syncthreads();

    for (int it = 0; it < 16; ++it) {
        const int cur = it & 1;
        if (it < 15) {
            gload16(gA + (it + 1)*32, &As[cur ^ 1][wave*512]);
            rw0 = *(const floatx4*)(gW + (it + 1)*32);
            rw1 = *(const floatx4*)(gW + (it + 1)*32 + 4);
        }
        bf16x8 af[2], bfr[2];
        for (int mi = 0; mi < 2; mi++)
            af[mi]  = *(const bf16x8*)&As[cur][(waveM*32 + mi*16 + l16)*32 + quad*8];
        for (int ni = 0; ni < 2; ni++)
            bfr[ni] = *(const bf16x8*)&Bs[cur][(waveN*32 + ni*16 + l16)*32 + quad*8];
        for (int mi = 0; mi < 2; mi++)
            for (int ni = 0; ni < 2; ni++)
                acc[mi][ni] = MFMA16(af[mi], bfr[ni], acc[mi][ni]);
        if (it < 15)
            *(bf16x8*)&Bs[cur ^ 1][srow*32 + scol] = cvt8(rw0, rw1);
        __syncthreads();   // drains gload_lds (vmcnt) and ds_writes
    }

    for (int ni = 0; ni < 2; ni++) {
        const int n = nBase + waveN*32 + ni*16 + l16;
        const float bv = bias[n];
        for (int mi = 0; mi < 2; mi++) {
            const int m0 = mBase + waveM*32 + mi*16 + quad*4;
            for (int rr = 0; rr < 4; rr++)
                Out[(size_t)(m0 + rr)*DIM + n] = acc[mi][ni][rr] + bv;
        }
    }
}

extern "C" void kernel_launch(void* const* d_in, const int* in_sizes, int n_in,
                              void* d_out, int out_size, void* d_ws, size_t ws_size,
                              hipStream_t stream) {
    const float* x      = (const float*)d_in[0];   // [2,4096,512] fp32
    const float* w_qkv  = (const float*)d_in[1];   // [1536,512] fp32
    const float* b_qkv  = (const float*)d_in[2];   // [1536] fp32
    const float* w_proj = (const float*)d_in[3];   // [512,512] fp32
    const float* b_proj = (const float*)d_in[4];   // [512] fp32
    float* out = (float*)d_out;                    // [2,4096,512] fp32

    __bf16* ws  = (__bf16*)d_ws;
    const size_t PLANE = (size_t)16 * SEQ * HD;    // 4 Mi elements = 8 MB
    __bf16* Qbk = ws;                 // Qblk [16][256][2][64][8] (pre-scaled)
    __bf16* Kbk = ws + PLANE;         // Kblk [16][256][2][64][8]
    __bf16* Vbk = ws + 2*PLANE;       // Vblk [16][128][4][64][8]
    __bf16* Aob = ws + 3*PLANE;       // [2,4096,512] attention output (bf16)

    gemm_qkv<<<dim3(64, 12), 256, 0, stream>>>(x, w_qkv, b_qkv, Qbk, Kbk, Vbk);
    attn_kernel<<<dim3(1024), 256, 0, stream>>>(Qbk, Kbk, Vbk, Aob);
    gemm_proj<<<dim3(128, 8), 256, 0, stream>>>(Aob, w_proj, b_proj, out);
}

// Round 6
// 194.561 us; speedup vs baseline: 1.9631x; 1.0843x over previous
//
#include <hip/hip_runtime.h>

typedef __bf16 bf16x8 __attribute__((ext_vector_type(8)));
typedef __bf16 bf16x4 __attribute__((ext_vector_type(4)));
typedef __bf16 bf16x2 __attribute__((ext_vector_type(2)));
typedef float  floatx4 __attribute__((ext_vector_type(4)));
typedef unsigned int uint32;
typedef uint32 uintx4 __attribute__((ext_vector_type(4)));

#define MFMA16(a,b,c) __builtin_amdgcn_mfma_f32_16x16x32_bf16(a,b,c,0,0,0)

constexpr int DIM  = 512;
constexpr int SEQ  = 4096;
constexpr int HD   = 64;
// 0.125 (HEAD_DIM^-0.5) * log2(e), folded into Q so softmax uses exp2 directly
constexpr float QSCALE = 0.1803368801111244f;

static __device__ inline __bf16 f2bf(float f) {
    unsigned int u = __builtin_bit_cast(unsigned int, f);
    u += 0x7fffu + ((u >> 16) & 1u);
    return __builtin_bit_cast(__bf16, (unsigned short)(u >> 16));
}
#if __has_builtin(__builtin_amdgcn_cvt_pk_bf16_f32)
static __device__ inline bf16x2 pk2(float a, float b) {
    return __builtin_amdgcn_cvt_pk_bf16_f32(a, b);
}
#else
static __device__ inline bf16x2 pk2(float a, float b) {
    bf16x2 r; r[0] = f2bf(a); r[1] = f2bf(b); return r;
}
#endif
#if __has_builtin(__builtin_amdgcn_exp2f)
#define EXP2(x) __builtin_amdgcn_exp2f(x)
#else
#define EXP2(x) exp2f(x)
#endif
static __device__ inline bf16x8 cvt8(floatx4 lo, floatx4 hi) {
    uintx4 w;
    w[0] = __builtin_bit_cast(uint32, pk2(lo[0], lo[1]));
    w[1] = __builtin_bit_cast(uint32, pk2(lo[2], lo[3]));
    w[2] = __builtin_bit_cast(uint32, pk2(hi[0], hi[1]));
    w[3] = __builtin_bit_cast(uint32, pk2(hi[2], hi[3]));
    return __builtin_bit_cast(bf16x8, w);
}

// async global->LDS, 16B per lane; LDS dest = wave-uniform base + lane*16B
static __device__ inline void gload16(const __bf16* g, __bf16* l) {
#if __has_builtin(__builtin_amdgcn_global_load_lds)
    __builtin_amdgcn_global_load_lds(
        (const __attribute__((address_space(1))) unsigned int*)g,
        (__attribute__((address_space(3))) unsigned int*)l, 16, 0, 0);
#else
    *(bf16x8*)(l + (threadIdx.x & 63)*8) = *(const bf16x8*)g;
#endif
}

// Blocked fragment layout for Q and K (A/B-operand ready, b128 loads):
//   blk[bh][s>>4][d>>5][lane][8], lane = ((d>>3)&3)*16 + (s&15), slot = d&7
// V blocked under key-permutation pi(q,j)=16*(j>=4)+4q+(j&3):
//   Vblk[bh][s>>5][d>>4][lane][8], lane = ((s>>2)&3)*16 + (d&15),
//   slot j = (s&3) + ((s>>4)&1)*4.

// ---------------------------------------------------------------------------
// Stage 0 (R6 new): one-shot fp32 -> bf16 conversion of X, W_qkv, W_proj
// into row-major bf16.  Same pk2 (v_cvt_pk_bf16_f32) rounding that the GEMMs
// used inline -> MFMA inputs bit-identical.  Removes all VALU cvt + register
// round-trips from the GEMM hot loops (X was re-converted 12x, W_qkv 64x).
// ---------------------------------------------------------------------------
__global__ __launch_bounds__(256)
void cvt_bf16(const float* __restrict__ X, const float* __restrict__ Wq,
              const float* __restrict__ Wp,
              __bf16* __restrict__ Xb, __bf16* __restrict__ Wqb,
              __bf16* __restrict__ Wpb)
{
    const int slice = blockIdx.y;
    const float* src;
    __bf16* dst;
    int n8;
    if (slice == 0)      { src = X;  dst = Xb;  n8 = (2*SEQ*DIM)/8; }
    else if (slice == 1) { src = Wq; dst = Wqb; n8 = (3*DIM*DIM)/8; }
    else                 { src = Wp; dst = Wpb; n8 = (DIM*DIM)/8; }
    const int i = blockIdx.x * 256 + threadIdx.x;
    if (i >= n8) return;
    const floatx4 lo = *(const floatx4*)(src + (size_t)i*8);
    const floatx4 hi = *(const floatx4*)(src + (size_t)i*8 + 4);
    *(bf16x8*)(dst + (size_t)i*8) = cvt8(lo, hi);
}

// ---------------------------------------------------------------------------
// Stage 1: qkv = x @ w_qkv^T + b_qkv.  R6: pure-bf16 m97 structure — both
// A and B tiles staged via global_load_lds (no VALU staging), double-buffered
// LDS, 1 barrier/iter.  Epilogues (verified blocked layouts) unchanged.
// ---------------------------------------------------------------------------
__global__ __launch_bounds__(256)
void gemm_qkv(const __bf16* __restrict__ X, const __bf16* __restrict__ W,
              const float* __restrict__ bias,
              __bf16* __restrict__ Qb, __bf16* __restrict__ Kb, __bf16* __restrict__ Vb)
{
    __shared__ __bf16 As[2][128*32];
    __shared__ __bf16 Bs[2][128*32];
    const int tid  = threadIdx.x;
    const int lane = tid & 63;
    const int wave = tid >> 6;
    const int quad = lane >> 4;
    const int l16  = lane & 15;
    const int waveM = wave >> 1, waveN = wave & 1;
    const int mBase = blockIdx.x * 128;
    const int nBase = blockIdx.y * 128;
    const int which = nBase >> 9;          // 0=q 1=k 2=v (uniform per block)

    floatx4 zero = {0.f, 0.f, 0.f, 0.f};
    floatx4 acc[4][4];
    for (int i = 0; i < 4; i++)
        for (int j = 0; j < 4; j++) acc[i][j] = zero;

    const int lrow = lane >> 2;        // 0..15
    const int lcol = (lane & 3) * 8;   // 0,8,16,24

    const __bf16* ga = X + (size_t)(mBase + wave*16 + lrow)*DIM + lcol;
    const __bf16* gb = W + (size_t)(nBase + wave*16 + lrow)*DIM + lcol;

    auto STAGE = [&](int it, int b) {
        const int k0 = it * 32;
        gload16(ga + k0,            &As[b][(wave*16)*32]);
        gload16(ga + 64*DIM + k0,   &As[b][(64 + wave*16)*32]);
        gload16(gb + k0,            &Bs[b][(wave*16)*32]);
        gload16(gb + 64*DIM + k0,   &Bs[b][(64 + wave*16)*32]);
    };

    STAGE(0, 0);
    __syncthreads();    // drains vmcnt: buf0 ready

    for (int it = 0; it < 16; ++it) {
        const int cur = it & 1;
        if (it < 15) STAGE(it + 1, cur ^ 1);   // async into other buffer

        bf16x8 af[4], bfr[4];
        for (int mi = 0; mi < 4; mi++)
            af[mi]  = *(const bf16x8*)&As[cur][(waveM*64 + mi*16 + l16)*32 + quad*8];
        for (int ni = 0; ni < 4; ni++)
            bfr[ni] = *(const bf16x8*)&Bs[cur][(waveN*64 + ni*16 + l16)*32 + quad*8];
        if (which == 2) {
            for (int mi = 0; mi < 4; mi++)
                for (int ni = 0; ni < 4; ni++)
                    acc[mi][ni] = MFMA16(af[mi], bfr[ni], acc[mi][ni]);
        } else {
            // transposed: rows = W-rows (d), cols = X-rows (s)
            for (int mi = 0; mi < 4; mi++)
                for (int ni = 0; ni < 4; ni++)
                    acc[mi][ni] = MFMA16(bfr[ni], af[mi], acc[mi][ni]);
        }
        __syncthreads();   // all waves done reading cur; staged buf landed
    }

    if (which == 2) {
        // V epilogue (normal orientation): rows = s, cols = n/d
        for (int ni = 0; ni < 4; ni++) {
            const int n = nBase + waveN*64 + ni*16 + l16;
            const float bv = bias[n];
            const int h = (n >> 6) & 7;
            const int d = n & 63;
            for (int mi = 0; mi < 4; mi++) {
                const int m0 = mBase + waveM*64 + mi*16 + quad*4;
                const int b  = m0 >> 12;
                const int s0 = m0 & 4095;
                const int bh = (b << 3) | h;
                bf16x4 v;
                for (int rr = 0; rr < 4; rr++) v[rr] = f2bf(acc[mi][ni][rr] + bv);
                size_t off = (((((size_t)bh*128 + (s0 >> 5))*4 + (d >> 4))*64)
                              + ((s0 >> 2) & 3)*16 + (d & 15))*8 + ((s0 >> 4) & 1)*4;
                *(bf16x4*)&Vb[off] = v;
            }
        }
    } else {
        // Q/K epilogue (transposed): rows = d (quad*4+r), cols = s (l16)
        __bf16* dst = (which == 0) ? Qb : Kb;
        for (int ni = 0; ni < 4; ni++) {
            const int n0 = nBase + waveN*64 + ni*16 + quad*4;
            const floatx4 b4 = *(const floatx4*)&bias[n0];
            const int dfull = n0 & 511;           // 0..511 within q or k section
            const int h  = dfull >> 6;
            const int d0 = dfull & 63;            // 4-aligned
            const int lgrp = ((d0 >> 3) & 3)*16 + l16;
            const int half = d0 >> 5;
            const int slot = d0 & 7;              // 0 or 4
            for (int mi = 0; mi < 4; mi++) {
                const int m = mBase + waveM*64 + mi*16 + l16;
                const int b = m >> 12, s = m & 4095;
                const int bh = (b << 3) | h;
                bf16x4 v;
                for (int rr = 0; rr < 4; rr++) {
                    float val = acc[mi][ni][rr] + b4[rr];
                    if (which == 0) val *= QSCALE;
                    v[rr] = f2bf(val);
                }
                size_t off = ((((size_t)bh*256 + (s >> 4))*2 + half)*64 + lgrp)*8 + slot;
                *(bf16x4*)&dst[off] = v;
            }
        }
    }
}

// ---------------------------------------------------------------------------
// Stage 2: flash attention — R0 verified core, launch_bounds(256,3) [NOT 4:
// unified VGPR+AGPR file -> ~164 regs/wave; forcing 4 waves/EU spills: R3
// measured FETCH 530MB, 267 µs].  1D grid + head->XCD clustering swizzle
// (R5: +1.8%, kept).  UNCHANGED from R5 (measured 80.6 µs).
// ---------------------------------------------------------------------------
__global__ __launch_bounds__(256, 3)
void attn_kernel(const __bf16* __restrict__ Qb, const __bf16* __restrict__ Kb,
                 const __bf16* __restrict__ Vb, __bf16* __restrict__ Ao)
{
    __shared__ __bf16 Ob[3][64*68];   // bf16 partial O^T, stride 68
    __shared__ float  Lb[4][64];
    const int tid  = threadIdx.x;
    const int lane = tid & 63;
    const int wave = tid >> 6;
    const int quad = lane >> 4;
    const int l16  = lane & 15;
    // XCD-clustering swizzle: id%8 selects XCD (round-robin dispatch); keep
    // it constant per head.  bh = (id&7) + 8*(slot>=64), qb = slot&63.
    const int id    = blockIdx.x;          // 0..1023
    const int slot  = id >> 3;             // 0..127
    const int bh    = (id & 7) + ((slot >> 6) << 3);
    const int qBase = (slot & 63) * 64;

    const __bf16* qg = Qb + (size_t)bh*256*2*512;
    const __bf16* kg = Kb + (size_t)bh*256*2*512;
    const __bf16* vg = Vb + (size_t)bh*128*4*512;

    bf16x8 qf[4][2];
    for (int t = 0; t < 4; t++)
        for (int hb = 0; hb < 2; hb++)
            qf[t][hb] = *(const bf16x8*)(qg
                + ((size_t)((qBase >> 4) + t)*2 + hb)*512 + lane*8);

    floatx4 zero = {0.f, 0.f, 0.f, 0.f};
    floatx4 oacc[4][4];   // [t][od]: O^T tile, row d=od*16+quad*4+r, col q=t*16+l16
    for (int t = 0; t < 4; t++)
        for (int od = 0; od < 4; od++) oacc[t][od] = zero;
    floatx4 Lt[4];        // ones-MFMA: every row of Lt[t] = L[q=t*16+l16]
    for (int t = 0; t < 4; t++) Lt[t] = zero;

    bf16x8 ones;
    for (int j = 0; j < 8; j++) ones[j] = f2bf(1.0f);

    const int key_begin = wave * 1024;
    const __bf16* kptr = kg + (size_t)(key_begin >> 4)*1024 + lane*8;
    const __bf16* vptr = vg + (size_t)(key_begin >> 5)*2048 + lane*8;

    for (int c = 0; c < 32; ++c) {
        bf16x8 kb00 = *(const bf16x8*)(kptr);
        bf16x8 kb01 = *(const bf16x8*)(kptr + 512);
        bf16x8 kb10 = *(const bf16x8*)(kptr + 1024);
        bf16x8 kb11 = *(const bf16x8*)(kptr + 1536);
        bf16x8 vb0  = *(const bf16x8*)(vptr);
        bf16x8 vb1  = *(const bf16x8*)(vptr + 512);
        bf16x8 vb2  = *(const bf16x8*)(vptr + 1024);
        bf16x8 vb3  = *(const bf16x8*)(vptr + 1536);
        kptr += 2048;
        vptr += 2048;

        for (int t = 0; t < 4; t++) {
            floatx4 z0 = zero, z1 = zero;
            z0 = MFMA16(kb00, qf[t][0], z0);
            z0 = MFMA16(kb01, qf[t][1], z0);
            z1 = MFMA16(kb10, qf[t][0], z1);
            z1 = MFMA16(kb11, qf[t][1], z1);
            float e0[4], e1[4];
            for (int r = 0; r < 4; r++) { e0[r] = EXP2(z0[r]); e1[r] = EXP2(z1[r]); }
            uintx4 w;
            w[0] = __builtin_bit_cast(uint32, pk2(e0[0], e0[1]));
            w[1] = __builtin_bit_cast(uint32, pk2(e0[2], e0[3]));
            w[2] = __builtin_bit_cast(uint32, pk2(e1[0], e1[1]));
            w[3] = __builtin_bit_cast(uint32, pk2(e1[2], e1[3]));
            bf16x8 pb = __builtin_bit_cast(bf16x8, w);
            Lt[t] = MFMA16(ones, pb, Lt[t]);
            oacc[t][0] = MFMA16(vb0, pb, oacc[t][0]);
            oacc[t][1] = MFMA16(vb1, pb, oacc[t][1]);
            oacc[t][2] = MFMA16(vb2, pb, oacc[t][2]);
            oacc[t][3] = MFMA16(vb3, pb, oacc[t][3]);
        }
    }

    // L[q] is replicated across rows of Lt[t]; publish per-wave partials
    if (lane < 16)
        for (int t = 0; t < 4; t++) Lb[wave][t*16 + lane] = Lt[t][0];
    __syncthreads();
    float inv[4];
    for (int t = 0; t < 4; t++) {
        const int q = t*16 + l16;
        inv[t] = 1.0f / (Lb[0][q] + Lb[1][q] + Lb[2][q] + Lb[3][q]);
    }
    if (wave != 0) {
        for (int t = 0; t < 4; t++)
            for (int od = 0; od < 4; od++) {
                bf16x4 v;
                for (int r = 0; r < 4; r++) v[r] = f2bf(oacc[t][od][r] * inv[t]);
                *(bf16x4*)&Ob[wave-1][(t*16 + l16)*68 + od*16 + quad*4] = v;
            }
    }
    __syncthreads();
    if (wave == 0) {
        const int b = bh >> 3, h = bh & 7;
        for (int t = 0; t < 4; t++) {
            const int s = qBase + t*16 + l16;
            for (int od = 0; od < 4; od++) {
                bf16x4 o0 = *(const bf16x4*)&Ob[0][(t*16 + l16)*68 + od*16 + quad*4];
                bf16x4 o1 = *(const bf16x4*)&Ob[1][(t*16 + l16)*68 + od*16 + quad*4];
                bf16x4 o2 = *(const bf16x4*)&Ob[2][(t*16 + l16)*68 + od*16 + quad*4];
                bf16x4 v;
                for (int r = 0; r < 4; r++) {
                    float o = oacc[t][od][r] * inv[t] +
                              (float)o0[r] + (float)o1[r] + (float)o2[r];
                    v[r] = f2bf(o);
                }
                *(bf16x4*)&Ao[((size_t)(b*SEQ + s))*DIM + h*HD + od*16 + quad*4] = v;
            }
        }
    }
}

// ---------------------------------------------------------------------------
// Stage 3: out = attn_out @ w_proj^T + b_proj.  R6: W pre-converted to bf16,
// both A and B via global_load_lds (zero staging VALU), double-buffered LDS,
// 1 barrier/iter.  64x64 tiles, grid (128,8) = 1024 blocks (4/CU).
// ---------------------------------------------------------------------------
__global__ __launch_bounds__(256)
void gemm_proj(const __bf16* __restrict__ A, const __bf16* __restrict__ W,
               const float* __restrict__ bias, float* __restrict__ Out)
{
    __shared__ __bf16 As[2][64*32];
    __shared__ __bf16 Bs[2][64*32];
    const int tid  = threadIdx.x;
    const int lane = tid & 63;
    const int wave = tid >> 6;
    const int quad = lane >> 4;
    const int l16  = lane & 15;
    const int waveM = wave >> 1, waveN = wave & 1;
    const int mBase = blockIdx.x * 64;
    const int nBase = blockIdx.y * 64;

    floatx4 zero = {0.f, 0.f, 0.f, 0.f};
    floatx4 acc[2][2];
    for (int i = 0; i < 2; i++)
        for (int j = 0; j < 2; j++) acc[i][j] = zero;

    const int lrow = lane >> 2;         // 0..15
    const int lcol = (lane & 3) * 8;    // 0,8,16,24

    const __bf16* gA = A + (size_t)(mBase + wave*16 + lrow)*DIM + lcol;
    const __bf16* gB = W + (size_t)(nBase + wave*16 + lrow)*DIM + lcol;

    auto STAGE = [&](int it, int b) {
        const int k0 = it * 32;
        gload16(gA + k0, &As[b][(wave*16)*32]);
        gload16(gB + k0, &Bs[b][(wave*16)*32]);
    };

    STAGE(0, 0);
    __syncthreads();

    for (int it = 0; it < 16; ++it) {
        const int cur = it & 1;
        if (it < 15) STAGE(it + 1, cur ^ 1);

        bf16x8 af[2], bfr[2];
        for (int mi = 0; mi < 2; mi++)
            af[mi]  = *(const bf16x8*)&As[cur][(waveM*32 + mi*16 + l16)*32 + quad*8];
        for (int ni = 0; ni < 2; ni++)
            bfr[ni] = *(const bf16x8*)&Bs[cur][(waveN*32 + ni*16 + l16)*32 + quad*8];
        for (int mi = 0; mi < 2; mi++)
            for (int ni = 0; ni < 2; ni++)
                acc[mi][ni] = MFMA16(af[mi], bfr[ni], acc[mi][ni]);
        __syncthreads();   // drains gload_lds (vmcnt); all waves done with cur
    }

    for (int ni = 0; ni < 2; ni++) {
        const int n = nBase + waveN*32 + ni*16 + l16;
        const float bv = bias[n];
        for (int mi = 0; mi < 2; mi++) {
            const int m0 = mBase + waveM*32 + mi*16 + quad*4;
            for (int rr = 0; rr < 4; rr++)
                Out[(size_t)(m0 + rr)*DIM + n] = acc[mi][ni][rr] + bv;
        }
    }
}

extern "C" void kernel_launch(void* const* d_in, const int* in_sizes, int n_in,
                              void* d_out, int out_size, void* d_ws, size_t ws_size,
                              hipStream_t stream) {
    const float* x      = (const float*)d_in[0];   // [2,4096,512] fp32
    const float* w_qkv  = (const float*)d_in[1];   // [1536,512] fp32
    const float* b_qkv  = (const float*)d_in[2];   // [1536] fp32
    const float* w_proj = (const float*)d_in[3];   // [512,512] fp32
    const float* b_proj = (const float*)d_in[4];   // [512] fp32
    float* out = (float*)d_out;                    // [2,4096,512] fp32

    __bf16* ws  = (__bf16*)d_ws;
    const size_t PLANE = (size_t)16 * SEQ * HD;    // 4 Mi elements = 8 MB
    __bf16* Qbk = ws;                 // Qblk [16][256][2][64][8] (pre-scaled)
    __bf16* Kbk = ws + PLANE;         // Kblk [16][256][2][64][8]
    __bf16* Vbk = ws + 2*PLANE;       // Vblk [16][128][4][64][8]
    __bf16* Aob = ws + 3*PLANE;       // [2,4096,512] attention output (bf16)
    __bf16* Xb  = ws + 4*PLANE;       // [8192,512] bf16 (row-major)
    __bf16* Wqb = ws + 5*PLANE;       // [1536,512] bf16
    __bf16* Wpb = ws + 5*PLANE + (size_t)3*DIM*DIM;  // [512,512] bf16

    cvt_bf16<<<dim3(2048, 3), 256, 0, stream>>>(x, w_qkv, w_proj, Xb, Wqb, Wpb);
    gemm_qkv<<<dim3(64, 12), 256, 0, stream>>>(Xb, Wqb, b_qkv, Qbk, Kbk, Vbk);
    attn_kernel<<<dim3(1024), 256, 0, stream>>>(Qbk, Kbk, Vbk, Aob);
    gemm_proj<<<dim3(128, 8), 256, 0, stream>>>(Aob, Wpb, b_proj, out);
}

// Round 7
// 192.725 us; speedup vs baseline: 1.9818x; 1.0095x over previous
//
#include <hip/hip_runtime.h>

typedef __bf16 bf16x8 __attribute__((ext_vector_type(8)));
typedef __bf16 bf16x4 __attribute__((ext_vector_type(4)));
typedef __bf16 bf16x2 __attribute__((ext_vector_type(2)));
typedef float  floatx4 __attribute__((ext_vector_type(4)));
typedef unsigned int uint32;
typedef uint32 uintx4 __attribute__((ext_vector_type(4)));

#define MFMA16(a,b,c) __builtin_amdgcn_mfma_f32_16x16x32_bf16(a,b,c,0,0,0)

constexpr int DIM  = 512;
constexpr int SEQ  = 4096;
constexpr int HD   = 64;
// 0.125 (HEAD_DIM^-0.5) * log2(e), folded into Q so softmax uses exp2 directly
constexpr float QSCALE = 0.1803368801111244f;

static __device__ inline __bf16 f2bf(float f) {
    unsigned int u = __builtin_bit_cast(unsigned int, f);
    u += 0x7fffu + ((u >> 16) & 1u);
    return __builtin_bit_cast(__bf16, (unsigned short)(u >> 16));
}
#if __has_builtin(__builtin_amdgcn_cvt_pk_bf16_f32)
static __device__ inline bf16x2 pk2(float a, float b) {
    return __builtin_amdgcn_cvt_pk_bf16_f32(a, b);
}
#else
static __device__ inline bf16x2 pk2(float a, float b) {
    bf16x2 r; r[0] = f2bf(a); r[1] = f2bf(b); return r;
}
#endif
#if __has_builtin(__builtin_amdgcn_exp2f)
#define EXP2(x) __builtin_amdgcn_exp2f(x)
#else
#define EXP2(x) exp2f(x)
#endif
static __device__ inline bf16x8 cvt8(floatx4 lo, floatx4 hi) {
    uintx4 w;
    w[0] = __builtin_bit_cast(uint32, pk2(lo[0], lo[1]));
    w[1] = __builtin_bit_cast(uint32, pk2(lo[2], lo[3]));
    w[2] = __builtin_bit_cast(uint32, pk2(hi[0], hi[1]));
    w[3] = __builtin_bit_cast(uint32, pk2(hi[2], hi[3]));
    return __builtin_bit_cast(bf16x8, w);
}

// async global->LDS, 16B per lane; LDS dest = wave-uniform base + lane*16B
static __device__ inline void gload16(const __bf16* g, __bf16* l) {
#if __has_builtin(__builtin_amdgcn_global_load_lds)
    __builtin_amdgcn_global_load_lds(
        (const __attribute__((address_space(1))) unsigned int*)g,
        (__attribute__((address_space(3))) unsigned int*)l, 16, 0, 0);
#else
    *(bf16x8*)(l + (threadIdx.x & 63)*8) = *(const bf16x8*)g;
#endif
}

// Blocked fragment layout for Q and K (A/B-operand ready, b128 loads):
//   blk[bh][s>>4][d>>5][lane][8], lane = ((d>>3)&3)*16 + (s&15), slot = d&7
// V blocked under key-permutation pi(q,j)=16*(j>=4)+4q+(j&3):
//   Vblk[bh][s>>5][d>>4][lane][8], lane = ((s>>2)&3)*16 + (d&15),
//   slot j = (s&3) + ((s>>4)&1)*4.

// ---------------------------------------------------------------------------
// Stage 0: one-shot fp32 -> bf16 conversion of X, W_qkv, W_proj (row-major).
// Same pk2 rounding the GEMMs used inline -> MFMA inputs bit-identical.
// ---------------------------------------------------------------------------
__global__ __launch_bounds__(256)
void cvt_bf16(const float* __restrict__ X, const float* __restrict__ Wq,
              const float* __restrict__ Wp,
              __bf16* __restrict__ Xb, __bf16* __restrict__ Wqb,
              __bf16* __restrict__ Wpb)
{
    const int slice = blockIdx.y;
    const float* src;
    __bf16* dst;
    int n8;
    if (slice == 0)      { src = X;  dst = Xb;  n8 = (2*SEQ*DIM)/8; }
    else if (slice == 1) { src = Wq; dst = Wqb; n8 = (3*DIM*DIM)/8; }
    else                 { src = Wp; dst = Wpb; n8 = (DIM*DIM)/8; }
    const int i = blockIdx.x * 256 + threadIdx.x;
    if (i >= n8) return;
    const floatx4 lo = *(const floatx4*)(src + (size_t)i*8);
    const floatx4 hi = *(const floatx4*)(src + (size_t)i*8 + 4);
    *(bf16x8*)(dst + (size_t)i*8) = cvt8(lo, hi);
}

// ---------------------------------------------------------------------------
// Stage 1: qkv = x @ w_qkv^T + b_qkv.  R7: T4 counted-vmcnt pipeline —
// 3 LDS buffers, STAGE issued 2 iters ahead, raw s_barrier with
// s_waitcnt vmcnt(4) (NOT the __syncthreads vmcnt(0) drain): the newest
// 4 gload_lds stay in flight across the barrier, so staging latency hides
// under a full iteration of MFMA instead of stalling every iter.
// lgkmcnt(0)+sched_barrier before the barrier pin this wave's ds_reads
// complete before buf[i%3] can be overwritten (earliest at iter i+1).
// Layouts/epilogues identical to R6.
// ---------------------------------------------------------------------------
__global__ __launch_bounds__(256)
void gemm_qkv(const __bf16* __restrict__ X, const __bf16* __restrict__ W,
              const float* __restrict__ bias,
              __bf16* __restrict__ Qb, __bf16* __restrict__ Kb, __bf16* __restrict__ Vb)
{
    __shared__ __bf16 As[3][128*32];   // 3 x 8KB
    __shared__ __bf16 Bs[3][128*32];   // 3 x 8KB   (48KB total -> 3 blocks/CU)
    const int tid  = threadIdx.x;
    const int lane = tid & 63;
    const int wave = tid >> 6;
    const int quad = lane >> 4;
    const int l16  = lane & 15;
    const int waveM = wave >> 1, waveN = wave & 1;
    const int mBase = blockIdx.x * 128;
    const int nBase = blockIdx.y * 128;
    const int which = nBase >> 9;          // 0=q 1=k 2=v (uniform per block)

    floatx4 zero = {0.f, 0.f, 0.f, 0.f};
    floatx4 acc[4][4];
    for (int i = 0; i < 4; i++)
        for (int j = 0; j < 4; j++) acc[i][j] = zero;

    const int lrow = lane >> 2;        // 0..15
    const int lcol = (lane & 3) * 8;   // 0,8,16,24

    const __bf16* ga = X + (size_t)(mBase + wave*16 + lrow)*DIM + lcol;
    const __bf16* gb = W + (size_t)(nBase + wave*16 + lrow)*DIM + lcol;

    auto STAGE = [&](int it, int b) {
        const int k0 = it * 32;
        gload16(ga + k0,            &As[b][(wave*16)*32]);
        gload16(ga + 64*DIM + k0,   &As[b][(64 + wave*16)*32]);
        gload16(gb + k0,            &Bs[b][(wave*16)*32]);
        gload16(gb + 64*DIM + k0,   &Bs[b][(64 + wave*16)*32]);
    };

    STAGE(0, 0);
    STAGE(1, 1);
    asm volatile("s_waitcnt vmcnt(4)" ::: "memory");  // S0 landed; S1 in flight
    __builtin_amdgcn_sched_barrier(0);
    __builtin_amdgcn_s_barrier();

    for (int it = 0; it < 16; ++it) {
        const int cur = it % 3;
        if (it < 14) STAGE(it + 2, (it + 2) % 3);

        bf16x8 af[4], bfr[4];
        for (int mi = 0; mi < 4; mi++)
            af[mi]  = *(const bf16x8*)&As[cur][(waveM*64 + mi*16 + l16)*32 + quad*8];
        for (int ni = 0; ni < 4; ni++)
            bfr[ni] = *(const bf16x8*)&Bs[cur][(waveN*64 + ni*16 + l16)*32 + quad*8];
        if (which == 2) {
            for (int mi = 0; mi < 4; mi++)
                for (int ni = 0; ni < 4; ni++)
                    acc[mi][ni] = MFMA16(af[mi], bfr[ni], acc[mi][ni]);
        } else {
            // transposed: rows = W-rows (d), cols = X-rows (s)
            for (int mi = 0; mi < 4; mi++)
                for (int ni = 0; ni < 4; ni++)
                    acc[mi][ni] = MFMA16(bfr[ni], af[mi], acc[mi][ni]);
        }

        if (it < 14)
            asm volatile("s_waitcnt vmcnt(4) lgkmcnt(0)" ::: "memory");
        else
            asm volatile("s_waitcnt vmcnt(0) lgkmcnt(0)" ::: "memory");
        __builtin_amdgcn_sched_barrier(0);
        if (it < 15) __builtin_amdgcn_s_barrier();
    }

    if (which == 2) {
        // V epilogue (normal orientation): rows = s, cols = n/d
        for (int ni = 0; ni < 4; ni++) {
            const int n = nBase + waveN*64 + ni*16 + l16;
            const float bv = bias[n];
            const int h = (n >> 6) & 7;
            const int d = n & 63;
            for (int mi = 0; mi < 4; mi++) {
                const int m0 = mBase + waveM*64 + mi*16 + quad*4;
                const int b  = m0 >> 12;
                const int s0 = m0 & 4095;
                const int bh = (b << 3) | h;
                bf16x4 v;
                for (int rr = 0; rr < 4; rr++) v[rr] = f2bf(acc[mi][ni][rr] + bv);
                size_t off = (((((size_t)bh*128 + (s0 >> 5))*4 + (d >> 4))*64)
                              + ((s0 >> 2) & 3)*16 + (d & 15))*8 + ((s0 >> 4) & 1)*4;
                *(bf16x4*)&Vb[off] = v;
            }
        }
    } else {
        // Q/K epilogue (transposed): rows = d (quad*4+r), cols = s (l16)
        __bf16* dst = (which == 0) ? Qb : Kb;
        for (int ni = 0; ni < 4; ni++) {
            const int n0 = nBase + waveN*64 + ni*16 + quad*4;
            const floatx4 b4 = *(const floatx4*)&bias[n0];
            const int dfull = n0 & 511;           // 0..511 within q or k section
            const int h  = dfull >> 6;
            const int d0 = dfull & 63;            // 4-aligned
            const int lgrp = ((d0 >> 3) & 3)*16 + l16;
            const int half = d0 >> 5;
            const int slot = d0 & 7;              // 0 or 4
            for (int mi = 0; mi < 4; mi++) {
                const int m = mBase + waveM*64 + mi*16 + l16;
                const int b = m >> 12, s = m & 4095;
                const int bh = (b << 3) | h;
                bf16x4 v;
                for (int rr = 0; rr < 4; rr++) {
                    float val = acc[mi][ni][rr] + b4[rr];
                    if (which == 0) val *= QSCALE;
                    v[rr] = f2bf(val);
                }
                size_t off = ((((size_t)bh*256 + (s >> 4))*2 + half)*64 + lgrp)*8 + slot;
                *(bf16x4*)&dst[off] = v;
            }
        }
    }
}

// ---------------------------------------------------------------------------
// Stage 2: flash attention — R0 verified core, launch_bounds(256,3) [NOT 4:
// unified VGPR+AGPR file -> ~164 regs/wave; forcing 4 waves/EU spills: R3
// measured FETCH 530MB, 267 µs].  1D grid + head->XCD clustering swizzle.
// UNCHANGED from R5/R6 (measured 80.6-82.8 µs).
// ---------------------------------------------------------------------------
__global__ __launch_bounds__(256, 3)
void attn_kernel(const __bf16* __restrict__ Qb, const __bf16* __restrict__ Kb,
                 const __bf16* __restrict__ Vb, __bf16* __restrict__ Ao)
{
    __shared__ __bf16 Ob[3][64*68];   // bf16 partial O^T, stride 68
    __shared__ float  Lb[4][64];
    const int tid  = threadIdx.x;
    const int lane = tid & 63;
    const int wave = tid >> 6;
    const int quad = lane >> 4;
    const int l16  = lane & 15;
    // XCD-clustering swizzle: id%8 selects XCD (round-robin dispatch); keep
    // it constant per head.  bh = (id&7) + 8*(slot>=64), qb = slot&63.
    const int id    = blockIdx.x;          // 0..1023
    const int slot  = id >> 3;             // 0..127
    const int bh    = (id & 7) + ((slot >> 6) << 3);
    const int qBase = (slot & 63) * 64;

    const __bf16* qg = Qb + (size_t)bh*256*2*512;
    const __bf16* kg = Kb + (size_t)bh*256*2*512;
    const __bf16* vg = Vb + (size_t)bh*128*4*512;

    bf16x8 qf[4][2];
    for (int t = 0; t < 4; t++)
        for (int hb = 0; hb < 2; hb++)
            qf[t][hb] = *(const bf16x8*)(qg
                + ((size_t)((qBase >> 4) + t)*2 + hb)*512 + lane*8);

    floatx4 zero = {0.f, 0.f, 0.f, 0.f};
    floatx4 oacc[4][4];   // [t][od]: O^T tile, row d=od*16+quad*4+r, col q=t*16+l16
    for (int t = 0; t < 4; t++)
        for (int od = 0; od < 4; od++) oacc[t][od] = zero;
    floatx4 Lt[4];        // ones-MFMA: every row of Lt[t] = L[q=t*16+l16]
    for (int t = 0; t < 4; t++) Lt[t] = zero;

    bf16x8 ones;
    for (int j = 0; j < 8; j++) ones[j] = f2bf(1.0f);

    const int key_begin = wave * 1024;
    const __bf16* kptr = kg + (size_t)(key_begin >> 4)*1024 + lane*8;
    const __bf16* vptr = vg + (size_t)(key_begin >> 5)*2048 + lane*8;

    for (int c = 0; c < 32; ++c) {
        bf16x8 kb00 = *(const bf16x8*)(kptr);
        bf16x8 kb01 = *(const bf16x8*)(kptr + 512);
        bf16x8 kb10 = *(const bf16x8*)(kptr + 1024);
        bf16x8 kb11 = *(const bf16x8*)(kptr + 1536);
        bf16x8 vb0  = *(const bf16x8*)(vptr);
        bf16x8 vb1  = *(const bf16x8*)(vptr + 512);
        bf16x8 vb2  = *(const bf16x8*)(vptr + 1024);
        bf16x8 vb3  = *(const bf16x8*)(vptr + 1536);
        kptr += 2048;
        vptr += 2048;

        for (int t = 0; t < 4; t++) {
            floatx4 z0 = zero, z1 = zero;
            z0 = MFMA16(kb00, qf[t][0], z0);
            z0 = MFMA16(kb01, qf[t][1], z0);
            z1 = MFMA16(kb10, qf[t][0], z1);
            z1 = MFMA16(kb11, qf[t][1], z1);
            float e0[4], e1[4];
            for (int r = 0; r < 4; r++) { e0[r] = EXP2(z0[r]); e1[r] = EXP2(z1[r]); }
            uintx4 w;
            w[0] = __builtin_bit_cast(uint32, pk2(e0[0], e0[1]));
            w[1] = __builtin_bit_cast(uint32, pk2(e0[2], e0[3]));
            w[2] = __builtin_bit_cast(uint32, pk2(e1[0], e1[1]));
            w[3] = __builtin_bit_cast(uint32, pk2(e1[2], e1[3]));
            bf16x8 pb = __builtin_bit_cast(bf16x8, w);
            Lt[t] = MFMA16(ones, pb, Lt[t]);
            oacc[t][0] = MFMA16(vb0, pb, oacc[t][0]);
            oacc[t][1] = MFMA16(vb1, pb, oacc[t][1]);
            oacc[t][2] = MFMA16(vb2, pb, oacc[t][2]);
            oacc[t][3] = MFMA16(vb3, pb, oacc[t][3]);
        }
    }

    // L[q] is replicated across rows of Lt[t]; publish per-wave partials
    if (lane < 16)
        for (int t = 0; t < 4; t++) Lb[wave][t*16 + lane] = Lt[t][0];
    __syncthreads();
    float inv[4];
    for (int t = 0; t < 4; t++) {
        const int q = t*16 + l16;
        inv[t] = 1.0f / (Lb[0][q] + Lb[1][q] + Lb[2][q] + Lb[3][q]);
    }
    if (wave != 0) {
        for (int t = 0; t < 4; t++)
            for (int od = 0; od < 4; od++) {
                bf16x4 v;
                for (int r = 0; r < 4; r++) v[r] = f2bf(oacc[t][od][r] * inv[t]);
                *(bf16x4*)&Ob[wave-1][(t*16 + l16)*68 + od*16 + quad*4] = v;
            }
    }
    __syncthreads();
    if (wave == 0) {
        const int b = bh >> 3, h = bh & 7;
        for (int t = 0; t < 4; t++) {
            const int s = qBase + t*16 + l16;
            for (int od = 0; od < 4; od++) {
                bf16x4 o0 = *(const bf16x4*)&Ob[0][(t*16 + l16)*68 + od*16 + quad*4];
                bf16x4 o1 = *(const bf16x4*)&Ob[1][(t*16 + l16)*68 + od*16 + quad*4];
                bf16x4 o2 = *(const bf16x4*)&Ob[2][(t*16 + l16)*68 + od*16 + quad*4];
                bf16x4 v;
                for (int r = 0; r < 4; r++) {
                    float o = oacc[t][od][r] * inv[t] +
                              (float)o0[r] + (float)o1[r] + (float)o2[r];
                    v[r] = f2bf(o);
                }
                *(bf16x4*)&Ao[((size_t)(b*SEQ + s))*DIM + h*HD + od*16 + quad*4] = v;
            }
        }
    }
}

// ---------------------------------------------------------------------------
// Stage 3: out = attn_out @ w_proj^T + b_proj.  R7: same T4 counted-vmcnt
// 3-buffer pipeline (2 loads/stage -> vmcnt(2)).  64x64 tiles, grid (128,8).
// ---------------------------------------------------------------------------
__global__ __launch_bounds__(256)
void gemm_proj(const __bf16* __restrict__ A, const __bf16* __restrict__ W,
               const float* __restrict__ bias, float* __restrict__ Out)
{
    __shared__ __bf16 As[3][64*32];
    __shared__ __bf16 Bs[3][64*32];   // 24KB total
    const int tid  = threadIdx.x;
    const int lane = tid & 63;
    const int wave = tid >> 6;
    const int quad = lane >> 4;
    const int l16  = lane & 15;
    const int waveM = wave >> 1, waveN = wave & 1;
    const int mBase = blockIdx.x * 64;
    const int nBase = blockIdx.y * 64;

    floatx4 zero = {0.f, 0.f, 0.f, 0.f};
    floatx4 acc[2][2];
    for (int i = 0; i < 2; i++)
        for (int j = 0; j < 2; j++) acc[i][j] = zero;

    const int lrow = lane >> 2;         // 0..15
    const int lcol = (lane & 3) * 8;    // 0,8,16,24

    const __bf16* gA = A + (size_t)(mBase + wave*16 + lrow)*DIM + lcol;
    const __bf16* gB = W + (size_t)(nBase + wave*16 + lrow)*DIM + lcol;

    auto STAGE = [&](int it, int b) {
        const int k0 = it * 32;
        gload16(gA + k0, &As[b][(wave*16)*32]);
        gload16(gB + k0, &Bs[b][(wave*16)*32]);
    };

    STAGE(0, 0);
    STAGE(1, 1);
    asm volatile("s_waitcnt vmcnt(2)" ::: "memory");  // S0 landed; S1 in flight
    __builtin_amdgcn_sched_barrier(0);
    __builtin_amdgcn_s_barrier();

    for (int it = 0; it < 16; ++it) {
        const int cur = it % 3;
        if (it < 14) STAGE(it + 2, (it + 2) % 3);

        bf16x8 af[2], bfr[2];
        for (int mi = 0; mi < 2; mi++)
            af[mi]  = *(const bf16x8*)&As[cur][(waveM*32 + mi*16 + l16)*32 + quad*8];
        for (int ni = 0; ni < 2; ni++)
            bfr[ni] = *(const bf16x8*)&Bs[cur][(waveN*32 + ni*16 + l16)*32 + quad*8];
        for (int mi = 0; mi < 2; mi++)
            for (int ni = 0; ni < 2; ni++)
                acc[mi][ni] = MFMA16(af[mi], bfr[ni], acc[mi][ni]);

        if (it < 14)
            asm volatile("s_waitcnt vmcnt(2) lgkmcnt(0)" ::: "memory");
        else
            asm volatile("s_waitcnt vmcnt(0) lgkmcnt(0)" ::: "memory");
        __builtin_amdgcn_sched_barrier(0);
        if (it < 15) __builtin_amdgcn_s_barrier();
    }

    for (int ni = 0; ni < 2; ni++) {
        const int n = nBase + waveN*32 + ni*16 + l16;
        const float bv = bias[n];
        for (int mi = 0; mi < 2; mi++) {
            const int m0 = mBase + waveM*32 + mi*16 + quad*4;
            for (int rr = 0; rr < 4; rr++)
                Out[(size_t)(m0 + rr)*DIM + n] = acc[mi][ni][rr] + bv;
        }
    }
}

extern "C" void kernel_launch(void* const* d_in, const int* in_sizes, int n_in,
                              void* d_out, int out_size, void* d_ws, size_t ws_size,
                              hipStream_t stream) {
    const float* x      = (const float*)d_in[0];   // [2,4096,512] fp32
    const float* w_qkv  = (const float*)d_in[1];   // [1536,512] fp32
    const float* b_qkv  = (const float*)d_in[2];   // [1536] fp32
    const float* w_proj = (const float*)d_in[3];   // [512,512] fp32
    const float* b_proj = (const float*)d_in[4];   // [512] fp32
    float* out = (float*)d_out;                    // [2,4096,512] fp32

    __bf16* ws  = (__bf16*)d_ws;
    const size_t PLANE = (size_t)16 * SEQ * HD;    // 4 Mi elements = 8 MB
    __bf16* Qbk = ws;                 // Qblk [16][256][2][64][8] (pre-scaled)
    __bf16* Kbk = ws + PLANE;         // Kblk [16][256][2][64][8]
    __bf16* Vbk = ws + 2*PLANE;       // Vblk [16][128][4][64][8]
    __bf16* Aob = ws + 3*PLANE;       // [2,4096,512] attention output (bf16)
    __bf16* Xb  = ws + 4*PLANE;       // [8192,512] bf16 (row-major)
    __bf16* Wqb = ws + 5*PLANE;       // [1536,512] bf16
    __bf16* Wpb = ws + 5*PLANE + (size_t)3*DIM*DIM;  // [512,512] bf16

    cvt_bf16<<<dim3(2048, 3), 256, 0, stream>>>(x, w_qkv, w_proj, Xb, Wqb, Wpb);
    gemm_qkv<<<dim3(64, 12), 256, 0, stream>>>(Xb, Wqb, b_qkv, Qbk, Kbk, Vbk);
    attn_kernel<<<dim3(1024), 256, 0, stream>>>(Qbk, Kbk, Vbk, Aob);
    gemm_proj<<<dim3(128, 8), 256, 0, stream>>>(Aob, Wpb, b_proj, out);
}

// Round 8
// 182.620 us; speedup vs baseline: 2.0915x; 1.0553x over previous
//
#include <hip/hip_runtime.h>

typedef __bf16 bf16x8 __attribute__((ext_vector_type(8)));
typedef __bf16 bf16x4 __attribute__((ext_vector_type(4)));
typedef __bf16 bf16x2 __attribute__((ext_vector_type(2)));
typedef float  floatx4 __attribute__((ext_vector_type(4)));
typedef unsigned int uint32;
typedef uint32 uintx4 __attribute__((ext_vector_type(4)));

#define MFMA16(a,b,c) __builtin_amdgcn_mfma_f32_16x16x32_bf16(a,b,c,0,0,0)

constexpr int DIM  = 512;
constexpr int SEQ  = 4096;
constexpr int HD   = 64;
// 0.125 (HEAD_DIM^-0.5) * log2(e), folded into Q so softmax uses exp2 directly
constexpr float QSCALE = 0.1803368801111244f;

static __device__ inline __bf16 f2bf(float f) {
    unsigned int u = __builtin_bit_cast(unsigned int, f);
    u += 0x7fffu + ((u >> 16) & 1u);
    return __builtin_bit_cast(__bf16, (unsigned short)(u >> 16));
}
#if __has_builtin(__builtin_amdgcn_cvt_pk_bf16_f32)
static __device__ inline bf16x2 pk2(float a, float b) {
    return __builtin_amdgcn_cvt_pk_bf16_f32(a, b);
}
#else
static __device__ inline bf16x2 pk2(float a, float b) {
    bf16x2 r; r[0] = f2bf(a); r[1] = f2bf(b); return r;
}
#endif
#if __has_builtin(__builtin_amdgcn_exp2f)
#define EXP2(x) __builtin_amdgcn_exp2f(x)
#else
#define EXP2(x) exp2f(x)
#endif
static __device__ inline bf16x8 cvt8(floatx4 lo, floatx4 hi) {
    uintx4 w;
    w[0] = __builtin_bit_cast(uint32, pk2(lo[0], lo[1]));
    w[1] = __builtin_bit_cast(uint32, pk2(lo[2], lo[3]));
    w[2] = __builtin_bit_cast(uint32, pk2(hi[0], hi[1]));
    w[3] = __builtin_bit_cast(uint32, pk2(hi[2], hi[3]));
    return __builtin_bit_cast(bf16x8, w);
}

// Blocked fragment layout (A/B-operand ready, b128 loads, zero conflicts):
//   blk[row>>4][k>>5][lane][8], lane = ((k>>3)&3)*16 + (row&15), slot = k&7
// For a 16-aligned row base R and k-step it (32 k per step):
//   frag = *(bf16x8*)&blk[(size_t)R*512 + it*512 + lane*8]   (512 = 64*8)
// Q/K use the same structure per head; V blocked under key-permutation
//   pi(q,j)=16*(j>=4)+4q+(j&3) (see attn epilogues below).

// ---------------------------------------------------------------------------
// Stage 0: fp32 -> bf16 conversion of X, W_qkv, W_proj DIRECTLY into the
// blocked fragment layout.  Thread i handles 8 consecutive elems of a row
// (d&7==0 -> exactly one [8] slot).  Same pk2 rounding -> bit-identical
// MFMA inputs.
// ---------------------------------------------------------------------------
__global__ __launch_bounds__(256)
void cvt_blk(const float* __restrict__ X, const float* __restrict__ Wq,
             const float* __restrict__ Wp,
             __bf16* __restrict__ Xb, __bf16* __restrict__ Wqb,
             __bf16* __restrict__ Wpb)
{
    const int slice = blockIdx.y;
    const float* src;
    __bf16* dst;
    int n8;
    if (slice == 0)      { src = X;  dst = Xb;  n8 = (2*SEQ*DIM)/8; }
    else if (slice == 1) { src = Wq; dst = Wqb; n8 = (3*DIM*DIM)/8; }
    else                 { src = Wp; dst = Wpb; n8 = (DIM*DIM)/8; }
    const int i = blockIdx.x * 256 + threadIdx.x;
    if (i >= n8) return;
    const int row = i >> 6;            // /64 (64 x 8-elem slots per 512-row)
    const int d0  = (i & 63) * 8;      // 0..504, 8-aligned
    const floatx4 lo = *(const floatx4*)(src + (size_t)i*8);
    const floatx4 hi = *(const floatx4*)(src + (size_t)i*8 + 4);
    const size_t off8 = ((size_t)(row >> 4)*16 + (d0 >> 5))*64
                        + ((d0 >> 3) & 3)*16 + (row & 15);
    *(bf16x8*)(dst + off8*8) = cvt8(lo, hi);
}

// ---------------------------------------------------------------------------
// Stage 1: qkv = x @ w_qkv^T + b_qkv.  R8: attn-style — NO LDS, NO barriers.
// Each wave loads its A/B fragments directly from the blocked-layout global
// arrays (64 lanes x 16B = 1KB contiguous per frag, L2-resident) and MFMAs.
// The compiler pipelines next-iter loads under current MFMAs (proven by the
// attn core).  Removes the 8-way LDS bank conflict of the [*][32] tile and
// the per-iter barrier entirely.  Epilogues identical to R6/R7.
// ---------------------------------------------------------------------------
__global__ __launch_bounds__(256)
void gemm_qkv(const __bf16* __restrict__ Xb, const __bf16* __restrict__ Wb,
              const float* __restrict__ bias,
              __bf16* __restrict__ Qb, __bf16* __restrict__ Kb, __bf16* __restrict__ Vb)
{
    const int tid  = threadIdx.x;
    const int lane = tid & 63;
    const int wave = tid >> 6;
    const int quad = lane >> 4;
    const int l16  = lane & 15;
    const int waveM = wave >> 1, waveN = wave & 1;
    const int mBase = blockIdx.x * 128;
    const int nBase = blockIdx.y * 128;
    const int which = nBase >> 9;          // 0=q 1=k 2=v (uniform per block)

    floatx4 zero = {0.f, 0.f, 0.f, 0.f};
    floatx4 acc[4][4];
    for (int i = 0; i < 4; i++)
        for (int j = 0; j < 4; j++) acc[i][j] = zero;

    const __bf16* ga = Xb + (size_t)(mBase + waveM*64)*512 + lane*8;
    const __bf16* gb = Wb + (size_t)(nBase + waveN*64)*512 + lane*8;

    for (int it = 0; it < 16; ++it) {
        bf16x8 af[4], bfr[4];
        for (int mi = 0; mi < 4; mi++)
            af[mi]  = *(const bf16x8*)(ga + mi*8192 + it*512);
        for (int ni = 0; ni < 4; ni++)
            bfr[ni] = *(const bf16x8*)(gb + ni*8192 + it*512);
        if (which == 2) {
            for (int mi = 0; mi < 4; mi++)
                for (int ni = 0; ni < 4; ni++)
                    acc[mi][ni] = MFMA16(af[mi], bfr[ni], acc[mi][ni]);
        } else {
            // transposed: rows = W-rows (d), cols = X-rows (s)
            for (int mi = 0; mi < 4; mi++)
                for (int ni = 0; ni < 4; ni++)
                    acc[mi][ni] = MFMA16(bfr[ni], af[mi], acc[mi][ni]);
        }
    }

    if (which == 2) {
        // V epilogue (normal orientation): rows = s, cols = n/d
        for (int ni = 0; ni < 4; ni++) {
            const int n = nBase + waveN*64 + ni*16 + l16;
            const float bv = bias[n];
            const int h = (n >> 6) & 7;
            const int d = n & 63;
            for (int mi = 0; mi < 4; mi++) {
                const int m0 = mBase + waveM*64 + mi*16 + quad*4;
                const int b  = m0 >> 12;
                const int s0 = m0 & 4095;
                const int bh = (b << 3) | h;
                bf16x4 v;
                for (int rr = 0; rr < 4; rr++) v[rr] = f2bf(acc[mi][ni][rr] + bv);
                size_t off = (((((size_t)bh*128 + (s0 >> 5))*4 + (d >> 4))*64)
                              + ((s0 >> 2) & 3)*16 + (d & 15))*8 + ((s0 >> 4) & 1)*4;
                *(bf16x4*)&Vb[off] = v;
            }
        }
    } else {
        // Q/K epilogue (transposed): rows = d (quad*4+r), cols = s (l16)
        __bf16* dst = (which == 0) ? Qb : Kb;
        for (int ni = 0; ni < 4; ni++) {
            const int n0 = nBase + waveN*64 + ni*16 + quad*4;
            const floatx4 b4 = *(const floatx4*)&bias[n0];
            const int dfull = n0 & 511;           // 0..511 within q or k section
            const int h  = dfull >> 6;
            const int d0 = dfull & 63;            // 4-aligned
            const int lgrp = ((d0 >> 3) & 3)*16 + l16;
            const int half = d0 >> 5;
            const int slot = d0 & 7;              // 0 or 4
            for (int mi = 0; mi < 4; mi++) {
                const int m = mBase + waveM*64 + mi*16 + l16;
                const int b = m >> 12, s = m & 4095;
                const int bh = (b << 3) | h;
                bf16x4 v;
                for (int rr = 0; rr < 4; rr++) {
                    float val = acc[mi][ni][rr] + b4[rr];
                    if (which == 0) val *= QSCALE;
                    v[rr] = f2bf(val);
                }
                size_t off = ((((size_t)bh*256 + (s >> 4))*2 + half)*64 + lgrp)*8 + slot;
                *(bf16x4*)&dst[off] = v;
            }
        }
    }
}

// ---------------------------------------------------------------------------
// Stage 2: flash attention — R0 verified core, launch_bounds(256,3) [NOT 4:
// unified VGPR+AGPR file -> ~164 regs/wave; forcing 4 waves/EU spills: R3
// measured FETCH 530MB, 267 µs].  1D grid + head->XCD clustering swizzle.
// R8 change: final store writes the BLOCKED layout (index permutation only,
// same values) so gemm_proj can frag-load its A operand directly.
// ---------------------------------------------------------------------------
__global__ __launch_bounds__(256, 3)
void attn_kernel(const __bf16* __restrict__ Qb, const __bf16* __restrict__ Kb,
                 const __bf16* __restrict__ Vb, __bf16* __restrict__ Ao)
{
    __shared__ __bf16 Ob[3][64*68];   // bf16 partial O^T, stride 68
    __shared__ float  Lb[4][64];
    const int tid  = threadIdx.x;
    const int lane = tid & 63;
    const int wave = tid >> 6;
    const int quad = lane >> 4;
    const int l16  = lane & 15;
    // XCD-clustering swizzle: id%8 selects XCD (round-robin dispatch); keep
    // it constant per head.  bh = (id&7) + 8*(slot>=64), qb = slot&63.
    const int id    = blockIdx.x;          // 0..1023
    const int slot  = id >> 3;             // 0..127
    const int bh    = (id & 7) + ((slot >> 6) << 3);
    const int qBase = (slot & 63) * 64;

    const __bf16* qg = Qb + (size_t)bh*256*2*512;
    const __bf16* kg = Kb + (size_t)bh*256*2*512;
    const __bf16* vg = Vb + (size_t)bh*128*4*512;

    bf16x8 qf[4][2];
    for (int t = 0; t < 4; t++)
        for (int hb = 0; hb < 2; hb++)
            qf[t][hb] = *(const bf16x8*)(qg
                + ((size_t)((qBase >> 4) + t)*2 + hb)*512 + lane*8);

    floatx4 zero = {0.f, 0.f, 0.f, 0.f};
    floatx4 oacc[4][4];   // [t][od]: O^T tile, row d=od*16+quad*4+r, col q=t*16+l16
    for (int t = 0; t < 4; t++)
        for (int od = 0; od < 4; od++) oacc[t][od] = zero;
    floatx4 Lt[4];        // ones-MFMA: every row of Lt[t] = L[q=t*16+l16]
    for (int t = 0; t < 4; t++) Lt[t] = zero;

    bf16x8 ones;
    for (int j = 0; j < 8; j++) ones[j] = f2bf(1.0f);

    const int key_begin = wave * 1024;
    const __bf16* kptr = kg + (size_t)(key_begin >> 4)*1024 + lane*8;
    const __bf16* vptr = vg + (size_t)(key_begin >> 5)*2048 + lane*8;

    for (int c = 0; c < 32; ++c) {
        bf16x8 kb00 = *(const bf16x8*)(kptr);
        bf16x8 kb01 = *(const bf16x8*)(kptr + 512);
        bf16x8 kb10 = *(const bf16x8*)(kptr + 1024);
        bf16x8 kb11 = *(const bf16x8*)(kptr + 1536);
        bf16x8 vb0  = *(const bf16x8*)(vptr);
        bf16x8 vb1  = *(const bf16x8*)(vptr + 512);
        bf16x8 vb2  = *(const bf16x8*)(vptr + 1024);
        bf16x8 vb3  = *(const bf16x8*)(vptr + 1536);
        kptr += 2048;
        vptr += 2048;

        for (int t = 0; t < 4; t++) {
            floatx4 z0 = zero, z1 = zero;
            z0 = MFMA16(kb00, qf[t][0], z0);
            z0 = MFMA16(kb01, qf[t][1], z0);
            z1 = MFMA16(kb10, qf[t][0], z1);
            z1 = MFMA16(kb11, qf[t][1], z1);
            float e0[4], e1[4];
            for (int r = 0; r < 4; r++) { e0[r] = EXP2(z0[r]); e1[r] = EXP2(z1[r]); }
            uintx4 w;
            w[0] = __builtin_bit_cast(uint32, pk2(e0[0], e0[1]));
            w[1] = __builtin_bit_cast(uint32, pk2(e0[2], e0[3]));
            w[2] = __builtin_bit_cast(uint32, pk2(e1[0], e1[1]));
            w[3] = __builtin_bit_cast(uint32, pk2(e1[2], e1[3]));
            bf16x8 pb = __builtin_bit_cast(bf16x8, w);
            Lt[t] = MFMA16(ones, pb, Lt[t]);
            oacc[t][0] = MFMA16(vb0, pb, oacc[t][0]);
            oacc[t][1] = MFMA16(vb1, pb, oacc[t][1]);
            oacc[t][2] = MFMA16(vb2, pb, oacc[t][2]);
            oacc[t][3] = MFMA16(vb3, pb, oacc[t][3]);
        }
    }

    // L[q] is replicated across rows of Lt[t]; publish per-wave partials
    if (lane < 16)
        for (int t = 0; t < 4; t++) Lb[wave][t*16 + lane] = Lt[t][0];
    __syncthreads();
    float inv[4];
    for (int t = 0; t < 4; t++) {
        const int q = t*16 + l16;
        inv[t] = 1.0f / (Lb[0][q] + Lb[1][q] + Lb[2][q] + Lb[3][q]);
    }
    if (wave != 0) {
        for (int t = 0; t < 4; t++)
            for (int od = 0; od < 4; od++) {
                bf16x4 v;
                for (int r = 0; r < 4; r++) v[r] = f2bf(oacc[t][od][r] * inv[t]);
                *(bf16x4*)&Ob[wave-1][(t*16 + l16)*68 + od*16 + quad*4] = v;
            }
    }
    __syncthreads();
    if (wave == 0) {
        const int b = bh >> 3, h = bh & 7;
        for (int t = 0; t < 4; t++) {
            // global row = b*4096 + qBase + t*16 + l16; row>>4 = b*256+qBase/16+t
            const size_t rtop = (size_t)b*256 + (qBase >> 4) + t;
            for (int od = 0; od < 4; od++) {
                bf16x4 o0 = *(const bf16x4*)&Ob[0][(t*16 + l16)*68 + od*16 + quad*4];
                bf16x4 o1 = *(const bf16x4*)&Ob[1][(t*16 + l16)*68 + od*16 + quad*4];
                bf16x4 o2 = *(const bf16x4*)&Ob[2][(t*16 + l16)*68 + od*16 + quad*4];
                bf16x4 v;
                for (int r = 0; r < 4; r++) {
                    float o = oacc[t][od][r] * inv[t] +
                              (float)o0[r] + (float)o1[r] + (float)o2[r];
                    v[r] = f2bf(o);
                }
                // c = h*64 + od*16 + quad*4 + r  ->  blocked offset:
                const size_t off8 = (rtop*16 + h*2 + (od >> 1))*64
                                    + ((od*2 + (quad >> 1)) & 3)*16 + l16;
                *(bf16x4*)&Ao[off8*8 + (quad & 1)*4] = v;
            }
        }
    }
}

// ---------------------------------------------------------------------------
// Stage 3: out = attn_out @ w_proj^T + b_proj.  R8: attn-style — no LDS, no
// barriers; A from blocked attn output, B from blocked W_proj.  64x64 tiles,
// grid (128,8) = 1024 blocks (4/CU, 16 waves/CU of TLP).
// ---------------------------------------------------------------------------
__global__ __launch_bounds__(256)
void gemm_proj(const __bf16* __restrict__ Ab, const __bf16* __restrict__ Wb,
               const float* __restrict__ bias, float* __restrict__ Out)
{
    const int tid  = threadIdx.x;
    const int lane = tid & 63;
    const int wave = tid >> 6;
    const int quad = lane >> 4;
    const int l16  = lane & 15;
    const int waveM = wave >> 1, waveN = wave & 1;
    const int mBase = blockIdx.x * 64;
    const int nBase = blockIdx.y * 64;

    floatx4 zero = {0.f, 0.f, 0.f, 0.f};
    floatx4 acc[2][2];
    for (int i = 0; i < 2; i++)
        for (int j = 0; j < 2; j++) acc[i][j] = zero;

    const __bf16* gA = Ab + (size_t)(mBase + waveM*32)*512 + lane*8;
    const __bf16* gB = Wb + (size_t)(nBase + waveN*32)*512 + lane*8;

    for (int it = 0; it < 16; ++it) {
        bf16x8 af[2], bfr[2];
        for (int mi = 0; mi < 2; mi++)
            af[mi]  = *(const bf16x8*)(gA + mi*8192 + it*512);
        for (int ni = 0; ni < 2; ni++)
            bfr[ni] = *(const bf16x8*)(gB + ni*8192 + it*512);
        for (int mi = 0; mi < 2; mi++)
            for (int ni = 0; ni < 2; ni++)
                acc[mi][ni] = MFMA16(af[mi], bfr[ni], acc[mi][ni]);
    }

    for (int ni = 0; ni < 2; ni++) {
        const int n = nBase + waveN*32 + ni*16 + l16;
        const float bv = bias[n];
        for (int mi = 0; mi < 2; mi++) {
            const int m0 = mBase + waveM*32 + mi*16 + quad*4;
            for (int rr = 0; rr < 4; rr++)
                Out[(size_t)(m0 + rr)*DIM + n] = acc[mi][ni][rr] + bv;
        }
    }
}

extern "C" void kernel_launch(void* const* d_in, const int* in_sizes, int n_in,
                              void* d_out, int out_size, void* d_ws, size_t ws_size,
                              hipStream_t stream) {
    const float* x      = (const float*)d_in[0];   // [2,4096,512] fp32
    const float* w_qkv  = (const float*)d_in[1];   // [1536,512] fp32
    const float* b_qkv  = (const float*)d_in[2];   // [1536] fp32
    const float* w_proj = (const float*)d_in[3];   // [512,512] fp32
    const float* b_proj = (const float*)d_in[4];   // [512] fp32
    float* out = (float*)d_out;                    // [2,4096,512] fp32

    __bf16* ws  = (__bf16*)d_ws;
    const size_t PLANE = (size_t)16 * SEQ * HD;    // 4 Mi elements = 8 MB
    __bf16* Qbk = ws;                 // Qblk [16][256][2][64][8] (pre-scaled)
    __bf16* Kbk = ws + PLANE;         // Kblk [16][256][2][64][8]
    __bf16* Vbk = ws + 2*PLANE;       // Vblk [16][128][4][64][8]
    __bf16* Aob = ws + 3*PLANE;       // attn out, blocked [512][16][64][8]
    __bf16* Xb  = ws + 4*PLANE;       // X blocked [512][16][64][8]
    __bf16* Wqb = ws + 5*PLANE;       // W_qkv blocked [96][16][64][8]
    __bf16* Wpb = ws + 5*PLANE + (size_t)3*DIM*DIM;  // W_proj blocked [32][16][64][8]

    cvt_blk<<<dim3(2048, 3), 256, 0, stream>>>(x, w_qkv, w_proj, Xb, Wqb, Wpb);
    gemm_qkv<<<dim3(64, 12), 256, 0, stream>>>(Xb, Wqb, b_qkv, Qbk, Kbk, Vbk);
    attn_kernel<<<dim3(1024), 256, 0, stream>>>(Qbk, Kbk, Vbk, Aob);
    gemm_proj<<<dim3(128, 8), 256, 0, stream>>>(Aob, Wpb, b_proj, out);
}